// Round 1
// 11895.995 us; speedup vs baseline: 1.0600x; 1.0600x over previous
//
#include <hip/hip_runtime.h>
#include <stdint.h>

#define T_ 1024
#define B_ 128
#define IN_ 100
#define H_ 200
#define RD 4      // pr ring depth (power of 2)
#define RDY 8     // y0 ring depth (power of 2)

typedef unsigned short u16;
typedef short bf16x8 __attribute__((ext_vector_type(8)));
typedef float f32x4  __attribute__((ext_vector_type(4)));

// ---------------- workspace layout (bytes) ----------------
#define OFF_Y1    0u            // u16 [1024][128][200]        52,428,800
#define OFF_Y0R   52428800u     // f32 [8][128][200]              819,200
#define OFF_PR0   53248000u     // f32 [4][8][50][64][4]        1,638,400
#define OFF_PR1   54886400u     // f32 [4][8][50][64][4]        1,638,400
#define OFF_PACK  56524800u     // u16 packs: whh0,whh1,wih0,wih1 1,331,200
#define OFF_CBF   57856000u     // u16 canonical [583300]       1,166,656
#define OFF_CH0   59022656u     // f32 [2][128][200]              204,800
#define OFF_CC0   59227456u     // f32 [2][128][200]              204,800
#define OFF_X0P   59432256u     // int[8]  x0 produced watermark
#define OFF_Y0P   59432320u     // int[8]  y0 produced watermark
#define OFF_CONS0 59432384u     // int[8]  L0 ring consumed watermark
#define OFF_CONS1 59432448u     // int[8]  L1 ring consumed watermark
#define OFF_C1X   59432512u     // int[1024][8] pr1 ready counters (target 2)
#define OFF_Y0C   59465280u     // int[1024][8] y0 staged counters (target 2)
#define OFF_FLAG  59498048u     // int dtype flag
#define WS_NEEDED 59498112u
// pack sub-offsets in u16 units relative to OFF_PACK
#define PK_WHH0 0
#define PK_WHH1 179200
#define PK_WIH0 358400
#define PK_WIH1 460800

__device__ __forceinline__ float bf2f(u16 u) {
    union { uint32_t i; float f; } v; v.i = ((uint32_t)u) << 16; return v.f;
}
__device__ __forceinline__ u16 f2bf(float f) {
    union { uint32_t i; float f; } v; v.f = f;
    uint32_t x = v.i;
    x += 0x7fff + ((x >> 16) & 1);
    return (u16)(x >> 16);
}
__device__ __forceinline__ void agst(float* p, float v) {
    __hip_atomic_store(p, v, __ATOMIC_RELAXED, __HIP_MEMORY_SCOPE_AGENT);
}
__device__ __forceinline__ float agld(const float* p) {
    return __hip_atomic_load((float*)p, __ATOMIC_RELAXED, __HIP_MEMORY_SCOPE_AGENT);
}
__device__ __forceinline__ void agsti(int* p, int v) {
    __hip_atomic_store(p, v, __ATOMIC_RELAXED, __HIP_MEMORY_SCOPE_AGENT);
}
__device__ __forceinline__ void spin_ge(int* p, int val, int* budget) {
    while (__hip_atomic_load(p, __ATOMIC_RELAXED, __HIP_MEMORY_SCOPE_AGENT) < val) {
        __builtin_amdgcn_s_sleep(1);
        if (--(*budget) < 0) return;
    }
}

// ---------- dtype detector ----------
__global__ void detect_kernel(const void* w, int* flag) {
    __shared__ int cnt;
    if (threadIdx.x == 0) cnt = 0;
    __syncthreads();
    const u16* p = (const u16*)w;
    int bad = 0;
    for (int e = 0; e < 16; ++e) {
        u16 u = p[threadIdx.x * 16 + e];
        int ex = (u >> 7) & 0xFF;
        float v = bf2f(u);
        float av = v < 0.f ? -v : v;
        if (ex == 0xFF || av > 0.5f) bad++;
    }
    atomicAdd(&cnt, bad);
    __syncthreads();
    if (threadIdx.x == 0) flag[0] = (cnt > 64) ? 1 : 0;
}

// ---------- canonicalize params (unchanged layout) ----------
__global__ void prep_kernel(const void* Wih0, const void* Whh0,
                            const void* bih0, const void* bhh0,
                            const void* Wih1, const void* Whh1,
                            const void* bih1, const void* bhh1,
                            const void* fcW,  const void* fcb,
                            const void* h0,   const void* c0,
                            u16* cbf, float* ch0, float* cc0, const int* flag)
{
    const int isf32 = *flag;
    const int N = 685700;
    for (int idx = blockIdx.x * 256 + threadIdx.x; idx < N; idx += gridDim.x * 256) {
        const void* src; int e = idx; u16* du = nullptr; float* df = nullptr;
        if (e < 80000)                 { src = Wih0; du = cbf; }
        else if ((e -= 80000) < 160000){ src = Whh0; du = cbf + 80000; }
        else if ((e -= 160000) < 800)  { src = bih0; du = cbf + 240000; }
        else if ((e -= 800) < 800)     { src = bhh0; du = cbf + 240800; }
        else if ((e -= 800) < 160000)  { src = Wih1; du = cbf + 241600; }
        else if ((e -= 160000) < 160000){ src = Whh1; du = cbf + 401600; }
        else if ((e -= 160000) < 800)  { src = bih1; du = cbf + 561600; }
        else if ((e -= 800) < 800)     { src = bhh1; du = cbf + 562400; }
        else if ((e -= 800) < 20000)   { src = fcW;  du = cbf + 563200; }
        else if ((e -= 20000) < 100)   { src = fcb;  du = cbf + 583200; }
        else if ((e -= 100) < 51200)   { src = h0;   df = ch0; }
        else         { e -= 51200;       src = c0;   df = cc0; }
        float v = isf32 ? ((const float*)src)[e] : bf2f(((const u16*)src)[e]);
        if (du) du[e] = f2bf(v); else df[e] = v;
    }
}

// ---------- pack weights into MFMA B-fragment order ----------
// r' = hc*4 + g (gate-interleaved outputs). tile (kt,nt): lane l, elem e holds
// W[r' = nt*16+(l&15)][k = kt*32 + (l>>4)*8 + e]  (k-pad -> 0)
__global__ void pack_kernel(const u16* __restrict__ cbf, u16* __restrict__ pw) {
    const int N = 665600;
    for (int idx = blockIdx.x * 256 + threadIdx.x; idx < N; idx += gridDim.x * 256) {
        int e = idx; const u16* src; int ld, koff, kmax, rel;
        if (e < 179200)                    { rel = e; src = cbf + 80000;  ld = 200; kmax = 200; koff = 0; }
        else if ((e -= 179200) < 179200)   { rel = e; src = cbf + 401600; ld = 200; kmax = 200; koff = 0; }
        else if ((e -= 179200) < 102400)   { rel = e; src = cbf + 0;      ld = 100; kmax = 100; koff = 0; }
        else { e -= 102400; const int kh = e / 102400; rel = e % 102400;
               src = cbf + 241600; ld = 200; kmax = 100; koff = kh * 100; }
        const int el = rel & 7, l = (rel >> 3) & 63, tile = rel >> 9;
        const int nt = tile % 50, kt = tile / 50;
        const int rp = nt * 16 + (l & 15), g = rp & 3, hc = rp >> 2;
        const int k = kt * 32 + ((l >> 4) << 3) + el;
        u16 v = 0;
        if (k < kmax) v = src[(g * 200 + hc) * ld + koff + k];
        pw[idx] = v;
    }
}

// ============================================================
// 40 persistent blocks x 512 threads:
//   bid 0-15 : cell blocks (L = bid>>3, i = bid&7), 16 batches each.
//              Full W_hh resident (VGPR frags + LDS frags). Recurrence is
//              block-private: h kept in LDS as hi/lo bf16 planes; per step
//              one MFMA sweep (16x800x224, hi+lo) + pointwise cell.
//              x-partials arrive via IC rings, prefetched 1 step ahead
//              directly into the MFMA accumulators.
//   bid 16-23: x0 blocks (i): inp @ W_ih0^T + biases -> pr0 ring (MFMA).
//   bid 24-39: x1 blocks (i,kh): y0 @ W_ih1^T (K half) -> pr1 ring
//              via atomicAdd (cell re-zeroes slots after consuming).
// All cross-block payloads: agent-scope relaxed atomics (IC-coherent),
// flags posted after __syncthreads drains (same discipline as before).
// ============================================================
__launch_bounds__(512, 2)
__global__ void lstm_pipe(const void* __restrict__ inp, char* __restrict__ ws,
                          const int* __restrict__ flag, void* __restrict__ out)
{
    __shared__ __align__(16) u16 smem[67392];   // 134,784 B

    u16*   y1buf  = (u16*)(ws + OFF_Y1);
    float* y0ring = (float*)(ws + OFF_Y0R);
    float* pr0    = (float*)(ws + OFF_PR0);
    float* pr1    = (float*)(ws + OFF_PR1);
    u16*   packs  = (u16*)(ws + OFF_PACK);
    const u16* cbf = (const u16*)(ws + OFF_CBF);
    const float* ch0 = (const float*)(ws + OFF_CH0);
    const float* cc0 = (const float*)(ws + OFF_CC0);
    int* x0prod = (int*)(ws + OFF_X0P);
    int* y0prod = (int*)(ws + OFF_Y0P);
    int* cons0  = (int*)(ws + OFF_CONS0);
    int* cons1  = (int*)(ws + OFF_CONS1);
    int* c1x    = (int*)(ws + OFF_C1X);
    int* y0c    = (int*)(ws + OFF_Y0C);

    const int isf32 = *flag;
    const int tid = threadIdx.x;
    const int bid = blockIdx.x;
    const int lane = tid & 63, wv = tid >> 6;
    const int lm = lane & 15, lq = lane >> 4;
    const int nslot = (wv < 2) ? 7 : 6;   // 50 N-tiles over 8 waves
    int budget = 1 << 22;

    if (bid < 16) {
        // ======================= CELL =======================
        const int L = bid >> 3, i = bid & 7, b0 = i * 16;
        u16* ldsB = smem;                               // 62 tiles * 512 u16
        u16* hls  = smem + 31744;                       // [2][16][264] bf16
        float* gls = (float*)(smem + 40192);            // [4][200][17] f32
        const u16* packW = packs + (L ? PK_WHH1 : PK_WHH0);

        // --- persistent VGPR B tiles: slots 0-4 all kt, slot5 kt0 ---
        bf16x8 Bv[36];
        #pragma unroll
        for (int s = 0; s < 7; ++s) {
            const int nt = (s < 6) ? (wv + 8 * s) : (48 + wv);
            #pragma unroll
            for (int kt = 0; kt < 7; ++kt) {
                if (s < 5) {
                    Bv[s * 7 + kt] = *(const bf16x8*)(packW + ((size_t)(kt * 50 + nt) * 64 + lane) * 8);
                } else if (s == 5 && kt == 0) {
                    Bv[35] = *(const bf16x8*)(packW + ((size_t)(kt * 50 + nt) * 64 + lane) * 8);
                }
            }
        }
        // --- LDS B tiles: slot5 kt1-6 (all waves) + slot6 kt0-6 (waves 0,1) ---
        for (int u = tid; u < 31744; u += 512) {
            const int eidx = u >> 9, off = u & 511;
            int kt, nt;
            if (eidx < 48) { kt = 1 + eidx % 6; nt = (eidx / 6) + 40; }
            else { const int e2 = eidx - 48; kt = e2 % 7; nt = 48 + e2 / 7; }
            ldsB[u] = packW[(size_t)(kt * 50 + nt) * 512 + off];
        }
        // --- h(-1) hi/lo planes (+ zero k-pad) ---
        for (int u = tid; u < 2 * 16 * 264; u += 512) {
            const int pl = u / (16 * 264), m = (u / 264) % 16, k = u % 264;
            u16 v = 0;
            if (k < 200) {
                const float h = ch0[L * B_ * H_ + (b0 + m) * H_ + k];
                const u16 hi = f2bf(h);
                v = pl ? f2bf(h - bf2f(hi)) : hi;
            }
            hls[u] = v;
        }
        // --- c state: thread owns cells idx = tid + 512*k7, idx = m*200+hc ---
        float c[7];
        #pragma unroll
        for (int k7 = 0; k7 < 7; ++k7) {
            const int idx = tid + 512 * k7;
            c[k7] = (idx < 3200) ? cc0[L * B_ * H_ + (b0 + idx / 200) * H_ + (idx % 200)] : 0.f;
        }
        // --- prefetch ring t=0 into accumulators ---
        f32x4 acc[7];
        if (L == 0) spin_ge(x0prod + i, 1, &budget);
        else        spin_ge(c1x + i, 2, &budget);
        {
            float* ring = (L ? pr1 : pr0) + (size_t)(0 * 8 + i) * 12800;
            #pragma unroll
            for (int s = 0; s < 7; ++s) if (s < nslot) {
                const int nt = (s < 6) ? (wv + 8 * s) : (48 + wv);
                float* p = ring + nt * 256 + lane * 4;
                acc[s][0] = agld(p + 0); acc[s][1] = agld(p + 1);
                acc[s][2] = agld(p + 2); acc[s][3] = agld(p + 3);
                if (L) { agst(p + 0, 0.f); agst(p + 1, 0.f); agst(p + 2, 0.f); agst(p + 3, 0.f); }
            }
        }
        __syncthreads();

        for (int t = 0; t < T_; ++t) {
            // ---- phase 1: h-GEMM (hi+lo), weights resident ----
            #pragma unroll
            for (int kt = 0; kt < 7; ++kt) {
                const int ha = lm * 264 + kt * 32 + 8 * lq;
                const bf16x8 Ahi = *(const bf16x8*)(hls + ha);
                const bf16x8 Alo = *(const bf16x8*)(hls + 16 * 264 + ha);
                #pragma unroll
                for (int s = 0; s < 7; ++s) if (s < nslot) {
                    bf16x8 Bt;
                    if (s < 5)                 Bt = Bv[s * 7 + kt];
                    else if (s == 5 && kt == 0) Bt = Bv[35];
                    else {
                        const int eidx = (s == 5) ? (wv * 6 + kt - 1) : (48 + wv * 7 + kt);
                        Bt = *(const bf16x8*)(ldsB + eidx * 512 + lane * 8);
                    }
                    acc[s] = __builtin_amdgcn_mfma_f32_16x16x32_bf16(Ahi, Bt, acc[s], 0, 0, 0);
                    acc[s] = __builtin_amdgcn_mfma_f32_16x16x32_bf16(Alo, Bt, acc[s], 0, 0, 0);
                }
            }
            // ---- phase 2: gates -> LDS ([g][hc][m], stride 17) ----
            #pragma unroll
            for (int s = 0; s < 7; ++s) if (s < nslot) {
                const int nt = (s < 6) ? (wv + 8 * s) : (48 + wv);
                const int g = lm & 3, hc = nt * 4 + (lm >> 2);
                float* gp = gls + g * 3400 + hc * 17 + 4 * lq;
                gp[0] = acc[s][0]; gp[1] = acc[s][1]; gp[2] = acc[s][2]; gp[3] = acc[s][3];
            }
            __syncthreads();   // B1
            // ---- phase 3a: spin + prefetch ring t+1 into acc ----
            if (t < T_ - 1) {
                if (L == 0) spin_ge(x0prod + i, t + 2, &budget);
                else        spin_ge(c1x + (t + 1) * 8 + i, 2, &budget);
                float* ring = (L ? pr1 : pr0) + (size_t)(((t + 1) & (RD - 1)) * 8 + i) * 12800;
                #pragma unroll
                for (int s = 0; s < 7; ++s) if (s < nslot) {
                    const int nt = (s < 6) ? (wv + 8 * s) : (48 + wv);
                    float* p = ring + nt * 256 + lane * 4;
                    acc[s][0] = agld(p + 0); acc[s][1] = agld(p + 1);
                    acc[s][2] = agld(p + 2); acc[s][3] = agld(p + 3);
                    if (L) { agst(p + 0, 0.f); agst(p + 1, 0.f); agst(p + 2, 0.f); agst(p + 3, 0.f); }
                }
            }
            if (L == 0 && t >= RDY) spin_ge(y0c + (t - RDY) * 8 + i, 2, &budget);
            // ---- phase 3b: pointwise LSTM cell ----
            #pragma unroll
            for (int k7 = 0; k7 < 7; ++k7) {
                const int idx = tid + 512 * k7;
                if (idx < 3200) {
                    const int m = idx / 200, hc = idx % 200;
                    float ig = gls[hc * 17 + m];
                    float fg = gls[3400 + hc * 17 + m];
                    float gg = gls[6800 + hc * 17 + m];
                    float og = gls[10200 + hc * 17 + m];
                    ig = (ig == ig) ? ig : 0.f;  fg = (fg == fg) ? fg : 0.f;
                    gg = (gg == gg) ? gg : 0.f;  og = (og == og) ? og : 0.f;
                    ig = 1.f / (1.f + __expf(-ig));
                    fg = 1.f / (1.f + __expf(-fg));
                    og = 1.f / (1.f + __expf(-og));
                    gg = tanhf(gg);
                    c[k7] = fg * c[k7] + ig * gg;
                    const float h = og * tanhf(c[k7]);
                    const u16 hi = f2bf(h);
                    hls[m * 264 + hc] = hi;
                    hls[(16 + m) * 264 + hc] = f2bf(h - bf2f(hi));
                    if (L == 0) {
                        agst(y0ring + ((size_t)(t & (RDY - 1)) * B_ + b0 + m) * H_ + hc, h);
                    } else {
                        y1buf[((size_t)t * B_ + b0 + m) * H_ + hc] = f2bf(h);
                    }
                    if (t == T_ - 1) {
                        const size_t base = (size_t)T_ * B_ * IN_;
                        const size_t o1 = base + (size_t)L * B_ * H_ + (size_t)(b0 + m) * H_ + hc;
                        const size_t o2 = base + 2 * (size_t)B_ * H_ + (size_t)L * B_ * H_
                                        + (size_t)(b0 + m) * H_ + hc;
                        if (isf32) { ((float*)out)[o1] = h; ((float*)out)[o2] = c[k7]; }
                        else       { ((u16*)out)[o1] = f2bf(h); ((u16*)out)[o2] = f2bf(c[k7]); }
                    }
                }
            }
            __syncthreads();   // B2: h(t)+gates consumed; stores drained
            if (tid == 0) {
                if (L == 0) { agsti(cons0 + i, t + 1); agsti(y0prod + i, t + 1); }
                else        { agsti(cons1 + i, t + 1); }
            }
        }
    } else {
        // ======================= X BLOCKS =======================
        const int isx0 = (bid < 24);
        const int i  = isx0 ? (bid - 16) : ((bid - 24) >> 1);
        const int kh = isx0 ? 0 : ((bid - 24) & 1);
        const int b0 = i * 16;
        u16* xst = smem;   // [2][16][136] bf16 hi/lo staging
        const u16* packW = packs + (isx0 ? PK_WIH0 : (PK_WIH1 + kh * 102400));

        bf16x8 Bx[28];
        #pragma unroll
        for (int s = 0; s < 7; ++s) {
            const int nt = (s < 6) ? (wv + 8 * s) : (48 + wv);
            #pragma unroll
            for (int kt = 0; kt < 4; ++kt)
                if (s < nslot)
                    Bx[s * 4 + kt] = *(const bf16x8*)(packW + ((size_t)(kt * 50 + nt) * 64 + lane) * 8);
        }
        float bias[7];
        #pragma unroll
        for (int s = 0; s < 7; ++s) {
            bias[s] = 0.f;
            if (s < nslot && (isx0 || kh == 0)) {
                const int nt = (s < 6) ? (wv + 8 * s) : (48 + wv);
                const int rp = nt * 16 + lm, g = rp & 3, hc = rp >> 2, R = g * 200 + hc;
                bias[s] = isx0 ? (bf2f(cbf[240000 + R]) + bf2f(cbf[240800 + R]))
                               : (bf2f(cbf[561600 + R]) + bf2f(cbf[562400 + R]));
            }
        }

        for (int t = 0; t < T_; ++t) {
            if (isx0) {
                if (t >= RD) spin_ge(cons0 + i, t - (RD - 1), &budget);
            } else {
                spin_ge(y0prod + i, t + 1, &budget);
                if (t >= RD) spin_ge(cons1 + i, t - (RD - 1), &budget);
            }
            // stage x (or y0 half) as hi/lo bf16, zero-padded to K=128
            for (int u = tid; u < 16 * 136; u += 512) {
                const int m = u / 136, k = u % 136;
                float v = 0.f;
                if (isx0) {
                    if (k < IN_) {
                        const size_t gi = ((size_t)t * B_ + b0 + m) * IN_ + k;
                        v = isf32 ? ((const float*)inp)[gi] : bf2f(((const u16*)inp)[gi]);
                    }
                } else {
                    if (k < 100)
                        v = agld(y0ring + ((size_t)(t & (RDY - 1)) * B_ + b0 + m) * H_ + kh * 100 + k);
                }
                const u16 hi = f2bf(v);
                xst[m * 136 + k] = hi;
                xst[(16 + m) * 136 + k] = f2bf(v - bf2f(hi));
            }
            __syncthreads();
            if (!isx0 && tid == 0)
                __hip_atomic_fetch_add(y0c + t * 8 + i, 1, __ATOMIC_RELAXED, __HIP_MEMORY_SCOPE_AGENT);
            // MFMA x-GEMM
            f32x4 acc[7];
            #pragma unroll
            for (int s = 0; s < 7; ++s) {
                acc[s][0] = bias[s]; acc[s][1] = bias[s];
                acc[s][2] = bias[s]; acc[s][3] = bias[s];
            }
            #pragma unroll
            for (int kt = 0; kt < 4; ++kt) {
                const int xa = lm * 136 + kt * 32 + 8 * lq;
                const bf16x8 Ahi = *(const bf16x8*)(xst + xa);
                const bf16x8 Alo = *(const bf16x8*)(xst + 16 * 136 + xa);
                #pragma unroll
                for (int s = 0; s < 7; ++s) if (s < nslot) {
                    acc[s] = __builtin_amdgcn_mfma_f32_16x16x32_bf16(Ahi, Bx[s * 4 + kt], acc[s], 0, 0, 0);
                    acc[s] = __builtin_amdgcn_mfma_f32_16x16x32_bf16(Alo, Bx[s * 4 + kt], acc[s], 0, 0, 0);
                }
            }
            // emit partials to ring (fragment order = consumer's acc order)
            float* ring = (isx0 ? pr0 : pr1) + (size_t)((t & (RD - 1)) * 8 + i) * 12800;
            #pragma unroll
            for (int s = 0; s < 7; ++s) if (s < nslot) {
                const int nt = (s < 6) ? (wv + 8 * s) : (48 + wv);
                float* p = ring + nt * 256 + lane * 4;
                if (isx0) {
                    agst(p + 0, acc[s][0]); agst(p + 1, acc[s][1]);
                    agst(p + 2, acc[s][2]); agst(p + 3, acc[s][3]);
                } else {
                    atomicAdd(p + 0, acc[s][0]); atomicAdd(p + 1, acc[s][1]);
                    atomicAdd(p + 2, acc[s][2]); atomicAdd(p + 3, acc[s][3]);
                }
            }
            __syncthreads();   // drain stores/atomics (and protect xst reuse)
            if (tid == 0) {
                if (isx0) agsti(x0prod + i, t + 1);
                else __hip_atomic_fetch_add(c1x + t * 8 + i, 1, __ATOMIC_RELAXED, __HIP_MEMORY_SCOPE_AGENT);
            }
        }
    }
}

// out[m][c] = sum_k y1[m][k] * fcW[c][k] + fcb[c]
__launch_bounds__(256)
__global__ void fc_kernel(const u16* __restrict__ y1, const u16* __restrict__ cbf,
                          const int* __restrict__ flag, void* __restrict__ out)
{
    __shared__ float y1s[16 * 201];
    const int isf32 = *flag;
    const u16* fcW = cbf + 563200;
    const u16* fcb = cbf + 583200;
    const int tid = threadIdx.x;
    const int m0 = blockIdx.x * 16;
    for (int idx = tid; idx < 16 * 200; idx += 256) {
        int r = idx / 200, k = idx % 200;
        y1s[r * 201 + k] = bf2f(y1[(size_t)(m0 + r) * 200 + k]);
    }
    __syncthreads();
    const int r = tid & 15, ct = tid >> 4;
    float acc[7] = {0.f, 0.f, 0.f, 0.f, 0.f, 0.f, 0.f};
    for (int k = 0; k < 200; ++k) {
        const float x = y1s[r * 201 + k];
        #pragma unroll
        for (int qn = 0; qn < 7; ++qn) {
            int cc = ct + 16 * qn;
            if (cc < 100) acc[qn] = fmaf(x, bf2f(fcW[cc * 200 + k]), acc[qn]);
        }
    }
    #pragma unroll
    for (int qn = 0; qn < 7; ++qn) {
        int cc = ct + 16 * qn;
        if (cc < 100) {
            float v = acc[qn] + bf2f(fcb[cc]);
            v = (v == v) ? v : 0.f;
            const size_t oi = (size_t)(m0 + r) * 100 + cc;
            if (isf32) ((float*)out)[oi] = v;
            else       ((u16*)out)[oi] = f2bf(v);
        }
    }
}

extern "C" void kernel_launch(void* const* d_in, const int* in_sizes, int n_in,
                              void* d_out, int out_size, void* d_ws, size_t ws_size,
                              hipStream_t stream)
{
    const void* inp  = d_in[0];
    const void* h0   = d_in[1];
    const void* c0   = d_in[2];
    const void* Wih0 = d_in[3];
    const void* Whh0 = d_in[4];
    const void* bih0 = d_in[5];
    const void* bhh0 = d_in[6];
    const void* Wih1 = d_in[7];
    const void* Whh1 = d_in[8];
    const void* bih1 = d_in[9];
    const void* bhh1 = d_in[10];
    const void* fcW  = d_in[11];
    const void* fcb  = d_in[12];

    if (ws_size < WS_NEEDED) return;   // fail visibly rather than corrupt

    char* ws = (char*)d_ws;
    u16*   cbf  = (u16*)(ws + OFF_CBF);
    float* ch0  = (float*)(ws + OFF_CH0);
    float* cc0  = (float*)(ws + OFF_CC0);
    u16*   pw   = (u16*)(ws + OFF_PACK);
    int*   flag = (int*)(ws + OFF_FLAG);
    u16*   y1buf= (u16*)(ws + OFF_Y1);

    hipMemsetAsync(ws, 0, WS_NEEDED, stream);

    detect_kernel<<<1, 256, 0, stream>>>(Wih0, flag);
    prep_kernel<<<512, 256, 0, stream>>>(Wih0, Whh0, bih0, bhh0,
                                         Wih1, Whh1, bih1, bhh1,
                                         fcW, fcb, h0, c0, cbf, ch0, cc0, flag);
    pack_kernel<<<256, 256, 0, stream>>>(cbf, pw);
    lstm_pipe<<<40, 512, 0, stream>>>(inp, ws, flag, d_out);
    fc_kernel<<<8192, 256, 0, stream>>>(y1buf, cbf, flag, d_out);
}

// Round 3
// 7376.528 us; speedup vs baseline: 1.7094x; 1.6127x over previous
//
#include <hip/hip_runtime.h>
#include <stdint.h>

#define T_ 1024
#define B_ 128
#define IN_ 100
#define H_ 200
#define RD 8      // pr ring depth (power of 2)
#define RDY 8     // y0 ring depth (power of 2)

typedef unsigned short u16;
typedef unsigned long long u64;
typedef short bf16x8 __attribute__((ext_vector_type(8)));
typedef float f32x4  __attribute__((ext_vector_type(4)));

// ---------------- workspace layout (bytes) ----------------
#define OFF_Y1    0u            // u16 [1024][128][200]        52,428,800
#define OFF_Y0R   52428800u     // f32 [8][128][200]              819,200
#define OFF_PR0   53248000u     // f32 [8][8][50][64][4]        3,276,800
#define OFF_PR1A  56524800u     // f32 [8][8][50][64][4]        3,276,800
#define OFF_PR1B  59801600u     // f32 [8][8][50][64][4]        3,276,800
#define OFF_PACK  63078400u     // u16 packs: whh0,whh1,wih0,wih1 1,331,200
#define OFF_CBF   64409600u     // u16 canonical [583300]       1,166,656
#define OFF_CH0   65576256u     // f32 [2][128][200]              204,800
#define OFF_CC0   65781056u     // f32 [2][128][200]              204,800
#define OFF_X0P   65985856u     // int[8]  x0 produced watermark
#define OFF_Y0P   65985920u     // int[8]  y0 produced watermark
#define OFF_CONS0 65985984u     // int[8]  L0 ring consumed watermark
#define OFF_CONS1 65986048u     // int[8]  L1 ring consumed watermark
#define OFF_C1X   65986112u     // int[1024][8] pr1 ready counters (target 2)
#define OFF_Y0C   66018880u     // int[1024][8] y0 staged counters (target 2)
#define OFF_FLAG  66051648u     // int dtype flag
#define WS_NEEDED 66051712u
// pack sub-offsets in u16 units relative to OFF_PACK
#define PK_WHH0 0
#define PK_WHH1 179200
#define PK_WIH0 358400
#define PK_WIH1 460800

__device__ __forceinline__ float bf2f(u16 u) {
    union { uint32_t i; float f; } v; v.i = ((uint32_t)u) << 16; return v.f;
}
__device__ __forceinline__ u16 f2bf(float f) {
    union { uint32_t i; float f; } v; v.f = f;
    uint32_t x = v.i;
    x += 0x7fff + ((x >> 16) & 1);
    return (u16)(x >> 16);
}
// 8-byte agent-scope relaxed payload movement (IC-coherent, 2 floats/op)
__device__ __forceinline__ void agst2(float* p, float a, float b) {
    union { u64 u; float f[2]; } v; v.f[0] = a; v.f[1] = b;
    __hip_atomic_store((u64*)p, v.u, __ATOMIC_RELAXED, __HIP_MEMORY_SCOPE_AGENT);
}
__device__ __forceinline__ float2 agld2(const float* p) {
    union { u64 u; float f[2]; } v;
    v.u = __hip_atomic_load((u64*)p, __ATOMIC_RELAXED, __HIP_MEMORY_SCOPE_AGENT);
    return make_float2(v.f[0], v.f[1]);
}
__device__ __forceinline__ void agsti(int* p, int v) {
    __hip_atomic_store(p, v, __ATOMIC_RELAXED, __HIP_MEMORY_SCOPE_AGENT);
}
__device__ __forceinline__ void spin_ge(int* p, int val, int* budget) {
    while (__hip_atomic_load(p, __ATOMIC_RELAXED, __HIP_MEMORY_SCOPE_AGENT) < val) {
        __builtin_amdgcn_s_sleep(1);
        if (--(*budget) < 0) return;
    }
}

// ---------- dtype detector ----------
__global__ void detect_kernel(const void* w, int* flag) {
    __shared__ int cnt;
    if (threadIdx.x == 0) cnt = 0;
    __syncthreads();
    const u16* p = (const u16*)w;
    int bad = 0;
    for (int e = 0; e < 16; ++e) {
        u16 u = p[threadIdx.x * 16 + e];
        int ex = (u >> 7) & 0xFF;
        float v = bf2f(u);
        float av = v < 0.f ? -v : v;
        if (ex == 0xFF || av > 0.5f) bad++;
    }
    atomicAdd(&cnt, bad);
    __syncthreads();
    if (threadIdx.x == 0) flag[0] = (cnt > 64) ? 1 : 0;
}

// ---------- canonicalize params ----------
__global__ void prep_kernel(const void* Wih0, const void* Whh0,
                            const void* bih0, const void* bhh0,
                            const void* Wih1, const void* Whh1,
                            const void* bih1, const void* bhh1,
                            const void* fcW,  const void* fcb,
                            const void* h0,   const void* c0,
                            u16* cbf, float* ch0, float* cc0, const int* flag)
{
    const int isf32 = *flag;
    const int N = 685700;
    for (int idx = blockIdx.x * 256 + threadIdx.x; idx < N; idx += gridDim.x * 256) {
        const void* src; int e = idx; u16* du = nullptr; float* df = nullptr;
        if (e < 80000)                 { src = Wih0; du = cbf; }
        else if ((e -= 80000) < 160000){ src = Whh0; du = cbf + 80000; }
        else if ((e -= 160000) < 800)  { src = bih0; du = cbf + 240000; }
        else if ((e -= 800) < 800)     { src = bhh0; du = cbf + 240800; }
        else if ((e -= 800) < 160000)  { src = Wih1; du = cbf + 241600; }
        else if ((e -= 160000) < 160000){ src = Whh1; du = cbf + 401600; }
        else if ((e -= 160000) < 800)  { src = bih1; du = cbf + 561600; }
        else if ((e -= 800) < 800)     { src = bhh1; du = cbf + 562400; }
        else if ((e -= 800) < 20000)   { src = fcW;  du = cbf + 563200; }
        else if ((e -= 20000) < 100)   { src = fcb;  du = cbf + 583200; }
        else if ((e -= 100) < 51200)   { src = h0;   df = ch0; }
        else         { e -= 51200;       src = c0;   df = cc0; }
        float v = isf32 ? ((const float*)src)[e] : bf2f(((const u16*)src)[e]);
        if (du) du[e] = f2bf(v); else df[e] = v;
    }
}

// ---------- pack weights into MFMA B-fragment order ----------
// r' = hc*4 + g. tile (kt,nt): lane l, elem e holds
// W[r' = nt*16+(l&15)][k = kt*32 + (l>>4)*8 + e]  (k-pad -> 0)
__global__ void pack_kernel(const u16* __restrict__ cbf, u16* __restrict__ pw) {
    const int N = 665600;
    for (int idx = blockIdx.x * 256 + threadIdx.x; idx < N; idx += gridDim.x * 256) {
        int e = idx; const u16* src; int ld, koff, kmax, rel;
        if (e < 179200)                    { rel = e; src = cbf + 80000;  ld = 200; kmax = 200; koff = 0; }
        else if ((e -= 179200) < 179200)   { rel = e; src = cbf + 401600; ld = 200; kmax = 200; koff = 0; }
        else if ((e -= 179200) < 102400)   { rel = e; src = cbf + 0;      ld = 100; kmax = 100; koff = 0; }
        else { e -= 102400; const int kh = e / 102400; rel = e % 102400;
               src = cbf + 241600; ld = 200; kmax = 100; koff = kh * 100; }
        const int el = rel & 7, l = (rel >> 3) & 63, tile = rel >> 9;
        const int nt = tile % 50, kt = tile / 50;
        const int rp = nt * 16 + (l & 15), g = rp & 3, hc = rp >> 2;
        const int k = kt * 32 + ((l >> 4) << 3) + el;
        u16 v = 0;
        if (k < kmax) v = src[(g * 200 + hc) * ld + koff + k];
        pw[idx] = v;
    }
}

// ============================================================
// 40 persistent blocks x 512 threads (1 block/CU; 8 waves):
//   bid 0-15 : cell blocks (L = bid>>3, i = bid&7): block-private recurrence,
//              full W_hh resident (VGPR + LDS fragments), hi/lo bf16 h-planes.
//   bid 16-23: x0 blocks: inp @ W_ih0^T + biases -> pr0 ring.
//   bid 24-39: x1 blocks (i,kh): y0 @ W_ih1^T half-K -> pr1a/pr1b rings
//              (separate rings per kh: NO atomicAdd, NO slot re-zeroing).
// All cross-block payloads are 8-byte agent-scope relaxed atomics; only
// thread 0 of a block ever spins on flags (poll-traffic fix); flags posted
// after __syncthreads vmcnt-drain (release), same discipline as before.
// ============================================================
__launch_bounds__(512, 1)
__global__ void lstm_pipe(const void* __restrict__ inp, char* __restrict__ ws,
                          const int* __restrict__ flag, void* __restrict__ out)
{
    __shared__ __align__(16) u16 smem[67392];   // 134,784 B

    u16*   y1buf  = (u16*)(ws + OFF_Y1);
    float* y0ring = (float*)(ws + OFF_Y0R);
    float* pr0    = (float*)(ws + OFF_PR0);
    float* pr1a   = (float*)(ws + OFF_PR1A);
    float* pr1b   = (float*)(ws + OFF_PR1B);
    u16*   packs  = (u16*)(ws + OFF_PACK);
    const u16* cbf = (const u16*)(ws + OFF_CBF);
    const float* ch0 = (const float*)(ws + OFF_CH0);
    const float* cc0 = (const float*)(ws + OFF_CC0);
    int* x0prod = (int*)(ws + OFF_X0P);
    int* y0prod = (int*)(ws + OFF_Y0P);
    int* cons0  = (int*)(ws + OFF_CONS0);
    int* cons1  = (int*)(ws + OFF_CONS1);
    int* c1x    = (int*)(ws + OFF_C1X);
    int* y0c    = (int*)(ws + OFF_Y0C);

    const int isf32 = *flag;
    const int tid = threadIdx.x;
    const int bid = blockIdx.x;
    const int lane = tid & 63, wv = tid >> 6;
    const int lm = lane & 15, lq = lane >> 4;
    const int nslot = (wv < 2) ? 7 : 6;   // 50 N-tiles over 8 waves
    int budget = 1 << 22;

    if (bid < 16) {
        // ======================= CELL =======================
        const int L = bid >> 3, i = bid & 7, b0 = i * 16;
        u16* ldsB = smem;                               // 62 tiles * 512 u16
        u16* hls  = smem + 31744;                       // [2][16][264] bf16
        float* gls = (float*)(smem + 40192);            // [4][200][17] f32
        const u16* packW = packs + (L ? PK_WHH1 : PK_WHH0);

        // --- persistent VGPR B tiles: slots 0-4 all kt, slot5 kt0 ---
        bf16x8 Bv[36];
        #pragma unroll
        for (int s = 0; s < 7; ++s) {
            const int nt = (s < 6) ? (wv + 8 * s) : (48 + wv);
            #pragma unroll
            for (int kt = 0; kt < 7; ++kt) {
                if (s < 5) {
                    Bv[s * 7 + kt] = *(const bf16x8*)(packW + ((size_t)(kt * 50 + nt) * 64 + lane) * 8);
                } else if (s == 5 && kt == 0) {
                    Bv[35] = *(const bf16x8*)(packW + ((size_t)(kt * 50 + nt) * 64 + lane) * 8);
                }
            }
        }
        // --- LDS B tiles: slot5 kt1-6 (all waves) + slot6 kt0-6 (waves 0,1) ---
        for (int u = tid; u < 31744; u += 512) {
            const int eidx = u >> 9, off = u & 511;
            int kt, nt;
            if (eidx < 48) { kt = 1 + eidx % 6; nt = (eidx / 6) + 40; }
            else { const int e2 = eidx - 48; kt = e2 % 7; nt = 48 + e2 / 7; }
            ldsB[u] = packW[(size_t)(kt * 50 + nt) * 512 + off];
        }
        // --- h(-1) hi/lo planes (+ zero k-pad) ---
        for (int u = tid; u < 2 * 16 * 264; u += 512) {
            const int pl = u / (16 * 264), m = (u / 264) % 16, k = u % 264;
            u16 v = 0;
            if (k < 200) {
                const float h = ch0[L * B_ * H_ + (b0 + m) * H_ + k];
                const u16 hi = f2bf(h);
                v = pl ? f2bf(h - bf2f(hi)) : hi;
            }
            hls[u] = v;
        }
        // --- c state: thread owns PAIRS p = tid + 512*k4, p -> (m, hc=2*(p%100)) ---
        float c2[4][2];
        #pragma unroll
        for (int k4 = 0; k4 < 4; ++k4) {
            const int p = tid + 512 * k4;
            c2[k4][0] = 0.f; c2[k4][1] = 0.f;
            if (p < 1600) {
                const int m = p / 100, hc = (p % 100) * 2;
                c2[k4][0] = cc0[L * B_ * H_ + (b0 + m) * H_ + hc];
                c2[k4][1] = cc0[L * B_ * H_ + (b0 + m) * H_ + hc + 1];
            }
        }
        // --- prefetch ring t=0 into accumulators ---
        f32x4 acc[7];
        if (tid == 0) {
            if (L == 0) spin_ge(x0prod + i, 1, &budget);
            else        spin_ge(c1x + i, 2, &budget);
        }
        __syncthreads();
        {
            const size_t roff = (size_t)(0 * 8 + i) * 12800;
            #pragma unroll
            for (int s = 0; s < 7; ++s) if (s < nslot) {
                const int nt = (s < 6) ? (wv + 8 * s) : (48 + wv);
                float* pa = ((L ? pr1a : pr0) + roff) + nt * 256 + lane * 4;
                const float2 a01 = agld2(pa);
                const float2 a23 = agld2(pa + 2);
                acc[s][0] = a01.x; acc[s][1] = a01.y;
                acc[s][2] = a23.x; acc[s][3] = a23.y;
                if (L) {
                    float* pb = (pr1b + roff) + nt * 256 + lane * 4;
                    const float2 b01 = agld2(pb);
                    const float2 b23 = agld2(pb + 2);
                    acc[s][0] += b01.x; acc[s][1] += b01.y;
                    acc[s][2] += b23.x; acc[s][3] += b23.y;
                }
            }
        }
        __syncthreads();

        for (int t = 0; t < T_; ++t) {
            // ---- phase 1: h-GEMM (hi+lo), weights resident ----
            #pragma unroll
            for (int kt = 0; kt < 7; ++kt) {
                const int ha = lm * 264 + kt * 32 + 8 * lq;
                const bf16x8 Ahi = *(const bf16x8*)(hls + ha);
                const bf16x8 Alo = *(const bf16x8*)(hls + 16 * 264 + ha);
                #pragma unroll
                for (int s = 0; s < 7; ++s) if (s < nslot) {
                    bf16x8 Bt;
                    if (s < 5)                 Bt = Bv[s * 7 + kt];
                    else if (s == 5 && kt == 0) Bt = Bv[35];
                    else {
                        const int eidx = (s == 5) ? (wv * 6 + kt - 1) : (48 + wv * 7 + kt);
                        Bt = *(const bf16x8*)(ldsB + eidx * 512 + lane * 8);
                    }
                    acc[s] = __builtin_amdgcn_mfma_f32_16x16x32_bf16(Ahi, Bt, acc[s], 0, 0, 0);
                    acc[s] = __builtin_amdgcn_mfma_f32_16x16x32_bf16(Alo, Bt, acc[s], 0, 0, 0);
                }
            }
            // ---- phase 2: gates -> LDS ([g][hc][m], stride 17) ----
            #pragma unroll
            for (int s = 0; s < 7; ++s) if (s < nslot) {
                const int nt = (s < 6) ? (wv + 8 * s) : (48 + wv);
                const int g = lm & 3, hc = nt * 4 + (lm >> 2);
                float* gp = gls + g * 3400 + hc * 17 + 4 * lq;
                gp[0] = acc[s][0]; gp[1] = acc[s][1]; gp[2] = acc[s][2]; gp[3] = acc[s][3];
            }
            __syncthreads();   // B1: gates visible
            // ---- spin (tid0 only), then all threads prefetch + pointwise ----
            if (tid == 0) {
                if (t < T_ - 1) {
                    if (L == 0) spin_ge(x0prod + i, t + 2, &budget);
                    else        spin_ge(c1x + (t + 1) * 8 + i, 2, &budget);
                }
                if (L == 0 && t >= RDY) spin_ge(y0c + (t - RDY) * 8 + i, 2, &budget);
            }
            __syncthreads();   // B1b: flags observed
            if (t < T_ - 1) {
                const size_t roff = (size_t)(((t + 1) & (RD - 1)) * 8 + i) * 12800;
                #pragma unroll
                for (int s = 0; s < 7; ++s) if (s < nslot) {
                    const int nt = (s < 6) ? (wv + 8 * s) : (48 + wv);
                    float* pa = ((L ? pr1a : pr0) + roff) + nt * 256 + lane * 4;
                    const float2 a01 = agld2(pa);
                    const float2 a23 = agld2(pa + 2);
                    acc[s][0] = a01.x; acc[s][1] = a01.y;
                    acc[s][2] = a23.x; acc[s][3] = a23.y;
                    if (L) {
                        float* pb = (pr1b + roff) + nt * 256 + lane * 4;
                        const float2 b01 = agld2(pb);
                        const float2 b23 = agld2(pb + 2);
                        acc[s][0] += b01.x; acc[s][1] += b01.y;
                        acc[s][2] += b23.x; acc[s][3] += b23.y;
                    }
                }
            }
            // ---- pointwise LSTM cell: thread owns 2 adjacent hc ----
            #pragma unroll
            for (int k4 = 0; k4 < 4; ++k4) {
                const int p = tid + 512 * k4;
                if (p < 1600) {
                    const int m = p / 100, hc = (p % 100) * 2;
                    float ig0 = gls[hc * 17 + m],        ig1 = gls[(hc + 1) * 17 + m];
                    float fg0 = gls[3400 + hc * 17 + m], fg1 = gls[3400 + (hc + 1) * 17 + m];
                    float gg0 = gls[6800 + hc * 17 + m], gg1 = gls[6800 + (hc + 1) * 17 + m];
                    float og0 = gls[10200 + hc * 17 + m],og1 = gls[10200 + (hc + 1) * 17 + m];
                    ig0 = (ig0 == ig0) ? ig0 : 0.f;  ig1 = (ig1 == ig1) ? ig1 : 0.f;
                    fg0 = (fg0 == fg0) ? fg0 : 0.f;  fg1 = (fg1 == fg1) ? fg1 : 0.f;
                    gg0 = (gg0 == gg0) ? gg0 : 0.f;  gg1 = (gg1 == gg1) ? gg1 : 0.f;
                    og0 = (og0 == og0) ? og0 : 0.f;  og1 = (og1 == og1) ? og1 : 0.f;
                    ig0 = 1.f / (1.f + __expf(-ig0)); ig1 = 1.f / (1.f + __expf(-ig1));
                    fg0 = 1.f / (1.f + __expf(-fg0)); fg1 = 1.f / (1.f + __expf(-fg1));
                    og0 = 1.f / (1.f + __expf(-og0)); og1 = 1.f / (1.f + __expf(-og1));
                    gg0 = tanhf(gg0); gg1 = tanhf(gg1);
                    c2[k4][0] = fg0 * c2[k4][0] + ig0 * gg0;
                    c2[k4][1] = fg1 * c2[k4][1] + ig1 * gg1;
                    const float h0v = og0 * tanhf(c2[k4][0]);
                    const float h1v = og1 * tanhf(c2[k4][1]);
                    const u16 hi0 = f2bf(h0v), hi1 = f2bf(h1v);
                    const u16 lo0 = f2bf(h0v - bf2f(hi0)), lo1 = f2bf(h1v - bf2f(hi1));
                    *(uint32_t*)(hls + m * 264 + hc) = (uint32_t)hi0 | ((uint32_t)hi1 << 16);
                    *(uint32_t*)(hls + (16 + m) * 264 + hc) = (uint32_t)lo0 | ((uint32_t)lo1 << 16);
                    if (L == 0) {
                        agst2(y0ring + ((size_t)(t & (RDY - 1)) * B_ + b0 + m) * H_ + hc, h0v, h1v);
                    } else {
                        *(uint32_t*)(y1buf + ((size_t)t * B_ + b0 + m) * H_ + hc)
                            = (uint32_t)hi0 | ((uint32_t)hi1 << 16);
                    }
                    if (t == T_ - 1) {
                        const size_t base = (size_t)T_ * B_ * IN_;
                        const size_t bb = (size_t)(b0 + m) * H_ + hc;
                        const size_t o1 = base + (size_t)L * B_ * H_ + bb;
                        const size_t o2 = base + 2 * (size_t)B_ * H_ + (size_t)L * B_ * H_ + bb;
                        if (isf32) {
                            ((float*)out)[o1] = h0v; ((float*)out)[o1 + 1] = h1v;
                            ((float*)out)[o2] = c2[k4][0]; ((float*)out)[o2 + 1] = c2[k4][1];
                        } else {
                            ((u16*)out)[o1] = hi0; ((u16*)out)[o1 + 1] = hi1;
                            ((u16*)out)[o2] = f2bf(c2[k4][0]); ((u16*)out)[o2 + 1] = f2bf(c2[k4][1]);
                        }
                    }
                }
            }
            __syncthreads();   // B2: h(t)+gates consumed; stores drained (release)
            if (tid == 0) {
                if (L == 0) { agsti(cons0 + i, t + 1); agsti(y0prod + i, t + 1); }
                else        { agsti(cons1 + i, t + 1); }
            }
        }
    } else {
        // ======================= X BLOCKS =======================
        const int isx0 = (bid < 24);
        const int i  = isx0 ? (bid - 16) : ((bid - 24) >> 1);
        const int kh = isx0 ? 0 : ((bid - 24) & 1);
        const int b0 = i * 16;
        u16* xst = smem;   // [2][16][136] bf16 hi/lo staging
        const u16* packW = packs + (isx0 ? PK_WIH0 : (PK_WIH1 + kh * 102400));

        bf16x8 Bx[28];
        #pragma unroll
        for (int s = 0; s < 7; ++s) {
            const int nt = (s < 6) ? (wv + 8 * s) : (48 + wv);
            #pragma unroll
            for (int kt = 0; kt < 4; ++kt)
                if (s < nslot)
                    Bx[s * 4 + kt] = *(const bf16x8*)(packW + ((size_t)(kt * 50 + nt) * 64 + lane) * 8);
        }
        float bias[7];
        #pragma unroll
        for (int s = 0; s < 7; ++s) {
            bias[s] = 0.f;
            if (s < nslot && (isx0 || kh == 0)) {
                const int nt = (s < 6) ? (wv + 8 * s) : (48 + wv);
                const int rp = nt * 16 + lm, g = rp & 3, hc = rp >> 2, R = g * 200 + hc;
                bias[s] = isx0 ? (bf2f(cbf[240000 + R]) + bf2f(cbf[240800 + R]))
                               : (bf2f(cbf[561600 + R]) + bf2f(cbf[562400 + R]));
            }
        }
        // zero staging (incl. k-pad 100..136) once; loop writes only k<100
        for (int u = tid; u < 2 * 16 * 136; u += 512) xst[u] = 0;
        __syncthreads();

        for (int t = 0; t < T_; ++t) {
            if (tid == 0) {
                if (isx0) {
                    if (t >= RD) spin_ge(cons0 + i, t - (RD - 1), &budget);
                } else {
                    spin_ge(y0prod + i, t + 1, &budget);
                    if (t >= RD) spin_ge(cons1 + i, t - (RD - 1), &budget);
                }
            }
            __syncthreads();   // S0: flags observed
            // stage x (or y0 half) as hi/lo bf16, PAIRS of k (8B moves)
            for (int u = tid; u < 800; u += 512) {
                const int m = u / 50, k = (u % 50) * 2;
                float v0, v1;
                if (isx0) {
                    const size_t gi = ((size_t)t * B_ + b0 + m) * IN_ + k;
                    if (isf32) {
                        const float2 xv = *(const float2*)((const float*)inp + gi);
                        v0 = xv.x; v1 = xv.y;
                    } else {
                        const uint32_t xv = *(const uint32_t*)((const u16*)inp + gi);
                        v0 = bf2f((u16)xv); v1 = bf2f((u16)(xv >> 16));
                    }
                } else {
                    const float2 yv = agld2(y0ring + ((size_t)(t & (RDY - 1)) * B_ + b0 + m) * H_ + kh * 100 + k);
                    v0 = yv.x; v1 = yv.y;
                }
                const u16 hi0 = f2bf(v0), hi1 = f2bf(v1);
                *(uint32_t*)(xst + m * 136 + k) = (uint32_t)hi0 | ((uint32_t)hi1 << 16);
                *(uint32_t*)(xst + (16 + m) * 136 + k)
                    = (uint32_t)f2bf(v0 - bf2f(hi0)) | ((uint32_t)f2bf(v1 - bf2f(hi1)) << 16);
            }
            __syncthreads();   // S1: staging done (y0 reads complete)
            if (!isx0 && tid == 0)
                __hip_atomic_fetch_add(y0c + t * 8 + i, 1, __ATOMIC_RELAXED, __HIP_MEMORY_SCOPE_AGENT);
            // MFMA x-GEMM
            f32x4 acc[7];
            #pragma unroll
            for (int s = 0; s < 7; ++s) {
                acc[s][0] = bias[s]; acc[s][1] = bias[s];
                acc[s][2] = bias[s]; acc[s][3] = bias[s];
            }
            #pragma unroll
            for (int kt = 0; kt < 4; ++kt) {
                const int xa = lm * 136 + kt * 32 + 8 * lq;
                const bf16x8 Ahi = *(const bf16x8*)(xst + xa);
                const bf16x8 Alo = *(const bf16x8*)(xst + 16 * 136 + xa);
                #pragma unroll
                for (int s = 0; s < 7; ++s) if (s < nslot) {
                    acc[s] = __builtin_amdgcn_mfma_f32_16x16x32_bf16(Ahi, Bx[s * 4 + kt], acc[s], 0, 0, 0);
                    acc[s] = __builtin_amdgcn_mfma_f32_16x16x32_bf16(Alo, Bx[s * 4 + kt], acc[s], 0, 0, 0);
                }
            }
            // emit partials to ring (8B stores; separate ring per kh)
            float* ring = (isx0 ? pr0 : (kh ? pr1b : pr1a))
                        + (size_t)((t & (RD - 1)) * 8 + i) * 12800;
            #pragma unroll
            for (int s = 0; s < 7; ++s) if (s < nslot) {
                const int nt = (s < 6) ? (wv + 8 * s) : (48 + wv);
                float* pp = ring + nt * 256 + lane * 4;
                agst2(pp, acc[s][0], acc[s][1]);
                agst2(pp + 2, acc[s][2], acc[s][3]);
            }
            __syncthreads();   // S2: ring stores drained (release)
            if (tid == 0) {
                if (isx0) agsti(x0prod + i, t + 1);
                else __hip_atomic_fetch_add(c1x + t * 8 + i, 1, __ATOMIC_RELAXED, __HIP_MEMORY_SCOPE_AGENT);
            }
        }
    }
}

// out[m][c] = sum_k y1[m][k] * fcW[c][k] + fcb[c]
__launch_bounds__(256)
__global__ void fc_kernel(const u16* __restrict__ y1, const u16* __restrict__ cbf,
                          const int* __restrict__ flag, void* __restrict__ out)
{
    __shared__ float y1s[16 * 201];
    const int isf32 = *flag;
    const u16* fcW = cbf + 563200;
    const u16* fcb = cbf + 583200;
    const int tid = threadIdx.x;
    const int m0 = blockIdx.x * 16;
    for (int idx = tid; idx < 16 * 200; idx += 256) {
        int r = idx / 200, k = idx % 200;
        y1s[r * 201 + k] = bf2f(y1[(size_t)(m0 + r) * 200 + k]);
    }
    __syncthreads();
    const int r = tid & 15, ct = tid >> 4;
    float acc[7] = {0.f, 0.f, 0.f, 0.f, 0.f, 0.f, 0.f};
    for (int k = 0; k < 200; ++k) {
        const float x = y1s[r * 201 + k];
        #pragma unroll
        for (int qn = 0; qn < 7; ++qn) {
            int cc = ct + 16 * qn;
            if (cc < 100) acc[qn] = fmaf(x, bf2f(fcW[cc * 200 + k]), acc[qn]);
        }
    }
    #pragma unroll
    for (int qn = 0; qn < 7; ++qn) {
        int cc = ct + 16 * qn;
        if (cc < 100) {
            float v = acc[qn] + bf2f(fcb[cc]);
            v = (v == v) ? v : 0.f;
            const size_t oi = (size_t)(m0 + r) * 100 + cc;
            if (isf32) ((float*)out)[oi] = v;
            else       ((u16*)out)[oi] = f2bf(v);
        }
    }
}

extern "C" void kernel_launch(void* const* d_in, const int* in_sizes, int n_in,
                              void* d_out, int out_size, void* d_ws, size_t ws_size,
                              hipStream_t stream)
{
    const void* inp  = d_in[0];
    const void* h0   = d_in[1];
    const void* c0   = d_in[2];
    const void* Wih0 = d_in[3];
    const void* Whh0 = d_in[4];
    const void* bih0 = d_in[5];
    const void* bhh0 = d_in[6];
    const void* Wih1 = d_in[7];
    const void* Whh1 = d_in[8];
    const void* bih1 = d_in[9];
    const void* bhh1 = d_in[10];
    const void* fcW  = d_in[11];
    const void* fcb  = d_in[12];

    if (ws_size < WS_NEEDED) return;   // fail visibly rather than corrupt

    char* ws = (char*)d_ws;
    u16*   cbf  = (u16*)(ws + OFF_CBF);
    float* ch0  = (float*)(ws + OFF_CH0);
    float* cc0  = (float*)(ws + OFF_CC0);
    u16*   pw   = (u16*)(ws + OFF_PACK);
    int*   flag = (int*)(ws + OFF_FLAG);
    u16*   y1buf= (u16*)(ws + OFF_Y1);

    hipMemsetAsync(ws, 0, WS_NEEDED, stream);

    detect_kernel<<<1, 256, 0, stream>>>(Wih0, flag);
    prep_kernel<<<512, 256, 0, stream>>>(Wih0, Whh0, bih0, bhh0,
                                         Wih1, Whh1, bih1, bhh1,
                                         fcW, fcb, h0, c0, cbf, ch0, cc0, flag);
    pack_kernel<<<256, 256, 0, stream>>>(cbf, pw);
    lstm_pipe<<<40, 512, 0, stream>>>(inp, ws, flag, d_out);
    fc_kernel<<<8192, 256, 0, stream>>>(y1buf, cbf, flag, d_out);
}

// Round 4
// 6473.113 us; speedup vs baseline: 1.9480x; 1.1396x over previous
//
#include <hip/hip_runtime.h>
#include <stdint.h>

#define T_ 1024
#define B_ 128
#define IN_ 100
#define H_ 200
#define RD 32      // pr ring depth (power of 2)
#define RDY 32     // y0 ring depth (power of 2)

typedef unsigned short u16;
typedef unsigned long long u64;
typedef short bf16x8 __attribute__((ext_vector_type(8)));
typedef float f32x4  __attribute__((ext_vector_type(4)));

// ---------------- workspace layout (bytes) ----------------
#define OFF_Y1    0u            // u16 [1024][128][200]        52,428,800
#define OFF_Y0R   52428800u     // f32 [32][128][200]           3,276,800
#define OFF_PR0   55705600u     // f32 [32][8][12800]          13,107,200
#define OFF_PR1A  68812800u     // f32 [32][8][12800]          13,107,200
#define OFF_PR1B  81920000u     // f32 [32][8][12800]          13,107,200
#define OFF_PACK  95027200u     // u16 packs 665,600            1,331,200
#define OFF_CBF   96358400u     // u16 canonical [583300]       1,166,656
#define OFF_CH0   97525056u     // f32 [2][128][200]              204,800
#define OFF_CC0   97729856u     // f32 [2][128][200]              204,800
#define OFF_FLG   97934656u     // watermark arrays + dtype flag    4,160
#define WS_NEEDED 97938816u
// flag sub-offsets (bytes from OFF_FLG); each array int[8] strided 16 ints
#define FO_X0P  0u       // x0 produced watermark (posted every 4)
#define FO_Y0P  512u     // L0 h produced watermark (every step)
#define FO_W1A  1024u    // x1 kh0 ring produced watermark
#define FO_W1B  1536u    // x1 kh1 ring produced watermark
#define FO_WY0A 2048u    // x1 kh0 y0-staged watermark
#define FO_WY0B 2560u    // x1 kh1 y0-staged watermark
#define FO_CN0  3072u    // L0 pr0 consumed watermark (every 8)
#define FO_CN1  3584u    // L1 pr1 consumed watermark (every 8)
#define FO_DTF  4096u    // dtype flag
// pack sub-offsets in u16 units relative to OFF_PACK
#define PK_WHH0 0
#define PK_WHH1 179200
#define PK_WIH0 358400
#define PK_WIH1 460800

__device__ __forceinline__ float bf2f(u16 u) {
    union { uint32_t i; float f; } v; v.i = ((uint32_t)u) << 16; return v.f;
}
__device__ __forceinline__ u16 f2bf(float f) {
    union { uint32_t i; float f; } v; v.f = f;
    uint32_t x = v.i;
    x += 0x7fff + ((x >> 16) & 1);
    return (u16)(x >> 16);
}
// 8-byte agent-scope relaxed payload movement (IC-coherent, 2 floats/op)
__device__ __forceinline__ void agst2(float* p, float a, float b) {
    union { u64 u; float f[2]; } v; v.f[0] = a; v.f[1] = b;
    __hip_atomic_store((u64*)p, v.u, __ATOMIC_RELAXED, __HIP_MEMORY_SCOPE_AGENT);
}
__device__ __forceinline__ float2 agld2(const float* p) {
    union { u64 u; float f[2]; } v;
    v.u = __hip_atomic_load((u64*)p, __ATOMIC_RELAXED, __HIP_MEMORY_SCOPE_AGENT);
    return make_float2(v.f[0], v.f[1]);
}
__device__ __forceinline__ void agsti(int* p, int v) {
    __hip_atomic_store(p, v, __ATOMIC_RELAXED, __HIP_MEMORY_SCOPE_AGENT);
}
__device__ __forceinline__ void spin_ge(int* p, int val, int* budget) {
    while (__hip_atomic_load(p, __ATOMIC_RELAXED, __HIP_MEMORY_SCOPE_AGENT) < val) {
        __builtin_amdgcn_s_sleep(1);
        if (--(*budget) < 0) return;
    }
}
// fast activations (error ~1e-6, far inside tolerance)
__device__ __forceinline__ float fsig(float x) {
    const float e = __expf(-x);                       // overflow -> inf -> rcp -> 0 (correct)
    return __builtin_amdgcn_rcpf(1.f + e);
}
__device__ __forceinline__ float ftanh(float x) {
    const float ax = __builtin_fabsf(x);
    const float e = __expf(-2.f * ax);                // (0,1]
    const float r = (1.f - e) * __builtin_amdgcn_rcpf(1.f + e);
    return __builtin_copysignf(r, x);
}

// ---------- dtype detector ----------
__global__ void detect_kernel(const void* w, int* flag) {
    __shared__ int cnt;
    if (threadIdx.x == 0) cnt = 0;
    __syncthreads();
    const u16* p = (const u16*)w;
    int bad = 0;
    for (int e = 0; e < 16; ++e) {
        u16 u = p[threadIdx.x * 16 + e];
        int ex = (u >> 7) & 0xFF;
        float v = bf2f(u);
        float av = v < 0.f ? -v : v;
        if (ex == 0xFF || av > 0.5f) bad++;
    }
    atomicAdd(&cnt, bad);
    __syncthreads();
    if (threadIdx.x == 0) flag[0] = (cnt > 64) ? 1 : 0;
}

// ---------- canonicalize params ----------
__global__ void prep_kernel(const void* Wih0, const void* Whh0,
                            const void* bih0, const void* bhh0,
                            const void* Wih1, const void* Whh1,
                            const void* bih1, const void* bhh1,
                            const void* fcW,  const void* fcb,
                            const void* h0,   const void* c0,
                            u16* cbf, float* ch0, float* cc0, const int* flag)
{
    const int isf32 = *flag;
    const int N = 685700;
    for (int idx = blockIdx.x * 256 + threadIdx.x; idx < N; idx += gridDim.x * 256) {
        const void* src; int e = idx; u16* du = nullptr; float* df = nullptr;
        if (e < 80000)                 { src = Wih0; du = cbf; }
        else if ((e -= 80000) < 160000){ src = Whh0; du = cbf + 80000; }
        else if ((e -= 160000) < 800)  { src = bih0; du = cbf + 240000; }
        else if ((e -= 800) < 800)     { src = bhh0; du = cbf + 240800; }
        else if ((e -= 800) < 160000)  { src = Wih1; du = cbf + 241600; }
        else if ((e -= 160000) < 160000){ src = Whh1; du = cbf + 401600; }
        else if ((e -= 160000) < 800)  { src = bih1; du = cbf + 561600; }
        else if ((e -= 800) < 800)     { src = bhh1; du = cbf + 562400; }
        else if ((e -= 800) < 20000)   { src = fcW;  du = cbf + 563200; }
        else if ((e -= 20000) < 100)   { src = fcb;  du = cbf + 583200; }
        else if ((e -= 100) < 51200)   { src = h0;   df = ch0; }
        else         { e -= 51200;       src = c0;   df = cc0; }
        float v = isf32 ? ((const float*)src)[e] : bf2f(((const u16*)src)[e]);
        if (du) du[e] = f2bf(v); else df[e] = v;
    }
}

// ---------- pack weights into MFMA B-fragment order ----------
// r' = hc*4 + g. tile (kt,nt): lane l, elem e holds
// W[r' = nt*16+(l&15)][k = kt*32 + (l>>4)*8 + e]  (k-pad -> 0)
__global__ void pack_kernel(const u16* __restrict__ cbf, u16* __restrict__ pw) {
    const int N = 665600;
    for (int idx = blockIdx.x * 256 + threadIdx.x; idx < N; idx += gridDim.x * 256) {
        int e = idx; const u16* src; int ld, koff, kmax, rel;
        if (e < 179200)                    { rel = e; src = cbf + 80000;  ld = 200; kmax = 200; koff = 0; }
        else if ((e -= 179200) < 179200)   { rel = e; src = cbf + 401600; ld = 200; kmax = 200; koff = 0; }
        else if ((e -= 179200) < 102400)   { rel = e; src = cbf + 0;      ld = 100; kmax = 100; koff = 0; }
        else { e -= 102400; const int kh = e / 102400; rel = e % 102400;
               src = cbf + 241600; ld = 200; kmax = 100; koff = kh * 100; }
        const int el = rel & 7, l = (rel >> 3) & 63, tile = rel >> 9;
        const int nt = tile % 50, kt = tile / 50;
        const int rp = nt * 16 + (l & 15), g = rp & 3, hc = rp >> 2;
        const int k = kt * 32 + ((l >> 4) << 3) + el;
        u16 v = 0;
        if (k < kmax) v = src[(g * 200 + hc) * ld + koff + k];
        pw[idx] = v;
    }
}

// ============================================================
// 40 persistent blocks x 512 threads (1 block/CU; 8 waves):
//   bid 0-15 : cell blocks (L = bid>>3, i = bid&7): block-private recurrence.
//   bid 16-23: x0 blocks: inp @ W_ih0^T + biases -> pr0 ring (depth 32).
//   bid 24-39: x1 blocks (i,kh): y0 @ W_ih1^T half-K -> pr1a/pr1b (depth 32),
//              double-buffered LDS staging: loads for t+1 issued before GEMM(t),
//              drained in the SAME barrier window as ring stores (one IC window).
// All flags are monotone agsti watermarks; flag checks are BATCHED (cells check
// every 8 steps); rings are deep enough that steady state never blocks.
// ============================================================
__launch_bounds__(512, 1)
__global__ void lstm_pipe(const void* __restrict__ inp, char* __restrict__ ws,
                          const int* __restrict__ flag, void* __restrict__ out)
{
    __shared__ __align__(16) u16 smem[67392];   // 134,784 B

    u16*   y1buf  = (u16*)(ws + OFF_Y1);
    float* y0ring = (float*)(ws + OFF_Y0R);
    float* pr0    = (float*)(ws + OFF_PR0);
    float* pr1a   = (float*)(ws + OFF_PR1A);
    float* pr1b   = (float*)(ws + OFF_PR1B);
    u16*   packs  = (u16*)(ws + OFF_PACK);
    const u16* cbf = (const u16*)(ws + OFF_CBF);
    const float* ch0 = (const float*)(ws + OFF_CH0);
    const float* cc0 = (const float*)(ws + OFF_CC0);

    const int isf32 = *flag;
    const int tid = threadIdx.x;
    const int bid = blockIdx.x;
    const int lane = tid & 63, wv = tid >> 6;
    const int lm = lane & 15, lq = lane >> 4;
    const int nslot = (wv < 2) ? 7 : 6;   // 50 N-tiles over 8 waves
    int budget = 1 << 22;

    if (bid < 16) {
        // ======================= CELL =======================
        const int L = bid >> 3, i = bid & 7, b0 = i * 16;
        const int FI = i * 16;
        int* fx0p = (int*)(ws + OFF_FLG + FO_X0P) + FI;
        int* fy0p = (int*)(ws + OFF_FLG + FO_Y0P) + FI;
        int* fw1a = (int*)(ws + OFF_FLG + FO_W1A) + FI;
        int* fw1b = (int*)(ws + OFF_FLG + FO_W1B) + FI;
        int* fwy0a= (int*)(ws + OFF_FLG + FO_WY0A) + FI;
        int* fwy0b= (int*)(ws + OFF_FLG + FO_WY0B) + FI;
        int* fcn0 = (int*)(ws + OFF_FLG + FO_CN0) + FI;
        int* fcn1 = (int*)(ws + OFF_FLG + FO_CN1) + FI;

        u16* ldsB = smem;                               // 62 tiles * 512 u16
        u16* hls  = smem + 31744;                       // [2][16][264] bf16
        float* gls = (float*)(smem + 40192);            // [4][200][17] f32
        const u16* packW = packs + (L ? PK_WHH1 : PK_WHH0);

        // --- persistent VGPR B tiles: slots 0-4 all kt, slot5 kt0 ---
        bf16x8 Bv[36];
        #pragma unroll
        for (int s = 0; s < 7; ++s) {
            const int nt = (s < 6) ? (wv + 8 * s) : (48 + wv);
            #pragma unroll
            for (int kt = 0; kt < 7; ++kt) {
                if (s < 5) {
                    Bv[s * 7 + kt] = *(const bf16x8*)(packW + ((size_t)(kt * 50 + nt) * 64 + lane) * 8);
                } else if (s == 5 && kt == 0) {
                    Bv[35] = *(const bf16x8*)(packW + ((size_t)(kt * 50 + nt) * 64 + lane) * 8);
                }
            }
        }
        // --- LDS B tiles: slot5 kt1-6 (all waves) + slot6 kt0-6 (waves 0,1) ---
        for (int u = tid; u < 31744; u += 512) {
            const int eidx = u >> 9, off = u & 511;
            int kt, nt;
            if (eidx < 48) { kt = 1 + eidx % 6; nt = (eidx / 6) + 40; }
            else { const int e2 = eidx - 48; kt = e2 % 7; nt = 48 + e2 / 7; }
            ldsB[u] = packW[(size_t)(kt * 50 + nt) * 512 + off];
        }
        // --- h(-1) hi/lo planes (+ zero k-pad) ---
        for (int u = tid; u < 2 * 16 * 264; u += 512) {
            const int pl = u / (16 * 264), m = (u / 264) % 16, k = u % 264;
            u16 v = 0;
            if (k < 200) {
                const float h = ch0[L * B_ * H_ + (b0 + m) * H_ + k];
                const u16 hi = f2bf(h);
                v = pl ? f2bf(h - bf2f(hi)) : hi;
            }
            hls[u] = v;
        }
        // --- c state: thread owns PAIRS p = tid + 512*k4 -> (m, hc=2*(p%100)) ---
        float c2[4][2];
        #pragma unroll
        for (int k4 = 0; k4 < 4; ++k4) {
            const int p = tid + 512 * k4;
            c2[k4][0] = 0.f; c2[k4][1] = 0.f;
            if (p < 1600) {
                const int m = p / 100, hc = (p % 100) * 2;
                c2[k4][0] = cc0[L * B_ * H_ + (b0 + m) * H_ + hc];
                c2[k4][1] = cc0[L * B_ * H_ + (b0 + m) * H_ + hc + 1];
            }
        }
        // --- prologue: wait slot 0 available, prefetch into acc ---
        f32x4 acc[7];
        if (tid == 0) {
            if (L == 0) spin_ge(fx0p, 1, &budget);
            else        { spin_ge(fw1a, 1, &budget); spin_ge(fw1b, 1, &budget); }
        }
        __syncthreads();
        {
            const size_t roff = (size_t)(0 * 8 + i) * 12800;
            #pragma unroll
            for (int s = 0; s < 7; ++s) if (s < nslot) {
                const int nt = (s < 6) ? (wv + 8 * s) : (48 + wv);
                float* pa = ((L ? pr1a : pr0) + roff) + nt * 256 + lane * 4;
                const float2 a01 = agld2(pa);
                const float2 a23 = agld2(pa + 2);
                acc[s][0] = a01.x; acc[s][1] = a01.y;
                acc[s][2] = a23.x; acc[s][3] = a23.y;
                if (L) {
                    float* pb = (pr1b + roff) + nt * 256 + lane * 4;
                    const float2 b01 = agld2(pb);
                    const float2 b23 = agld2(pb + 2);
                    acc[s][0] += b01.x; acc[s][1] += b01.y;
                    acc[s][2] += b23.x; acc[s][3] += b23.y;
                }
            }
        }
        __syncthreads();

        for (int t = 0; t < T_; ++t) {
            // ---- phase 1: h-GEMM (hi+lo), weights resident ----
            #pragma unroll
            for (int kt = 0; kt < 7; ++kt) {
                const int ha = lm * 264 + kt * 32 + 8 * lq;
                const bf16x8 Ahi = *(const bf16x8*)(hls + ha);
                const bf16x8 Alo = *(const bf16x8*)(hls + 16 * 264 + ha);
                #pragma unroll
                for (int s = 0; s < 7; ++s) if (s < nslot) {
                    bf16x8 Bt;
                    if (s < 5)                 Bt = Bv[s * 7 + kt];
                    else if (s == 5 && kt == 0) Bt = Bv[35];
                    else {
                        const int eidx = (s == 5) ? (wv * 6 + kt - 1) : (48 + wv * 7 + kt);
                        Bt = *(const bf16x8*)(ldsB + eidx * 512 + lane * 8);
                    }
                    acc[s] = __builtin_amdgcn_mfma_f32_16x16x32_bf16(Ahi, Bt, acc[s], 0, 0, 0);
                    acc[s] = __builtin_amdgcn_mfma_f32_16x16x32_bf16(Alo, Bt, acc[s], 0, 0, 0);
                }
            }
            // ---- phase 2: gates -> LDS ([g][hc][m], stride 17) ----
            #pragma unroll
            for (int s = 0; s < 7; ++s) if (s < nslot) {
                const int nt = (s < 6) ? (wv + 8 * s) : (48 + wv);
                const int g = lm & 3, hc = nt * 4 + (lm >> 2);
                float* gp = gls + g * 3400 + hc * 17 + 4 * lq;
                gp[0] = acc[s][0]; gp[1] = acc[s][1]; gp[2] = acc[s][2]; gp[3] = acc[s][3];
            }
            __syncthreads();   // B1: gates visible
            // ---- batched flag window (every 8 steps only) ----
            if ((t & 7) == 0) {
                if (tid == 0) {
                    int tgt = t + 9; if (tgt > T_) tgt = T_;
                    if (L == 0) {
                        spin_ge(fx0p, tgt, &budget);
                        spin_ge(fwy0a, t - 15, &budget);   // y0ring reuse safety
                        spin_ge(fwy0b, t - 15, &budget);
                    } else {
                        spin_ge(fw1a, tgt, &budget);
                        spin_ge(fw1b, tgt, &budget);
                    }
                }
                __syncthreads();   // B1b (only on checked steps)
            }
            // ---- prefetch ring slot t+1 into acc (flag guaranteed by batch) ----
            if (t < T_ - 1) {
                const size_t roff = (size_t)(((t + 1) & (RD - 1)) * 8 + i) * 12800;
                #pragma unroll
                for (int s = 0; s < 7; ++s) if (s < nslot) {
                    const int nt = (s < 6) ? (wv + 8 * s) : (48 + wv);
                    float* pa = ((L ? pr1a : pr0) + roff) + nt * 256 + lane * 4;
                    const float2 a01 = agld2(pa);
                    const float2 a23 = agld2(pa + 2);
                    acc[s][0] = a01.x; acc[s][1] = a01.y;
                    acc[s][2] = a23.x; acc[s][3] = a23.y;
                    if (L) {
                        float* pb = (pr1b + roff) + nt * 256 + lane * 4;
                        const float2 b01 = agld2(pb);
                        const float2 b23 = agld2(pb + 2);
                        acc[s][0] += b01.x; acc[s][1] += b01.y;
                        acc[s][2] += b23.x; acc[s][3] += b23.y;
                    }
                }
            }
            // ---- pointwise LSTM cell: thread owns 2 adjacent hc ----
            #pragma unroll
            for (int k4 = 0; k4 < 4; ++k4) {
                const int p = tid + 512 * k4;
                if (p < 1600) {
                    const int m = p / 100, hc = (p % 100) * 2;
                    float ig0 = gls[hc * 17 + m],        ig1 = gls[(hc + 1) * 17 + m];
                    float fg0 = gls[3400 + hc * 17 + m], fg1 = gls[3400 + (hc + 1) * 17 + m];
                    float gg0 = gls[6800 + hc * 17 + m], gg1 = gls[6800 + (hc + 1) * 17 + m];
                    float og0 = gls[10200 + hc * 17 + m],og1 = gls[10200 + (hc + 1) * 17 + m];
                    ig0 = (ig0 == ig0) ? ig0 : 0.f;  ig1 = (ig1 == ig1) ? ig1 : 0.f;
                    fg0 = (fg0 == fg0) ? fg0 : 0.f;  fg1 = (fg1 == fg1) ? fg1 : 0.f;
                    gg0 = (gg0 == gg0) ? gg0 : 0.f;  gg1 = (gg1 == gg1) ? gg1 : 0.f;
                    og0 = (og0 == og0) ? og0 : 0.f;  og1 = (og1 == og1) ? og1 : 0.f;
                    ig0 = fsig(ig0); ig1 = fsig(ig1);
                    fg0 = fsig(fg0); fg1 = fsig(fg1);
                    og0 = fsig(og0); og1 = fsig(og1);
                    gg0 = ftanh(gg0); gg1 = ftanh(gg1);
                    c2[k4][0] = fg0 * c2[k4][0] + ig0 * gg0;
                    c2[k4][1] = fg1 * c2[k4][1] + ig1 * gg1;
                    const float h0v = og0 * ftanh(c2[k4][0]);
                    const float h1v = og1 * ftanh(c2[k4][1]);
                    const u16 hi0 = f2bf(h0v), hi1 = f2bf(h1v);
                    const u16 lo0 = f2bf(h0v - bf2f(hi0)), lo1 = f2bf(h1v - bf2f(hi1));
                    *(uint32_t*)(hls + m * 264 + hc) = (uint32_t)hi0 | ((uint32_t)hi1 << 16);
                    *(uint32_t*)(hls + (16 + m) * 264 + hc) = (uint32_t)lo0 | ((uint32_t)lo1 << 16);
                    if (L == 0) {
                        agst2(y0ring + ((size_t)(t & (RDY - 1)) * B_ + b0 + m) * H_ + hc, h0v, h1v);
                    } else {
                        *(uint32_t*)(y1buf + ((size_t)t * B_ + b0 + m) * H_ + hc)
                            = (uint32_t)hi0 | ((uint32_t)hi1 << 16);
                    }
                    if (t == T_ - 1) {
                        const size_t base = (size_t)T_ * B_ * IN_;
                        const size_t bb = (size_t)(b0 + m) * H_ + hc;
                        const size_t o1 = base + (size_t)L * B_ * H_ + bb;
                        const size_t o2 = base + 2 * (size_t)B_ * H_ + (size_t)L * B_ * H_ + bb;
                        if (isf32) {
                            ((float*)out)[o1] = h0v; ((float*)out)[o1 + 1] = h1v;
                            ((float*)out)[o2] = c2[k4][0]; ((float*)out)[o2 + 1] = c2[k4][1];
                        } else {
                            ((u16*)out)[o1] = hi0; ((u16*)out)[o1 + 1] = hi1;
                            ((u16*)out)[o2] = f2bf(c2[k4][0]); ((u16*)out)[o2 + 1] = f2bf(c2[k4][1]);
                        }
                    }
                }
            }
            __syncthreads();   // B2: h(t) consumed; prefetch loads + y0 stores drained
            if (tid == 0) {
                if (L == 0) {
                    agsti(fy0p, t + 1);
                    if (((t + 1) & 7) == 0) agsti(fcn0, t + 1);
                } else {
                    if (((t + 1) & 7) == 0) agsti(fcn1, t + 1);
                }
            }
        }
    } else {
        // ======================= X BLOCKS =======================
        const int isx0 = (bid < 24);
        const int i  = isx0 ? (bid - 16) : ((bid - 24) >> 1);
        const int kh = isx0 ? 0 : ((bid - 24) & 1);
        const int b0 = i * 16;
        const int FI = i * 16;
        int* fx0p = (int*)(ws + OFF_FLG + FO_X0P) + FI;
        int* fy0p = (int*)(ws + OFF_FLG + FO_Y0P) + FI;
        int* fw1  = (int*)(ws + OFF_FLG + (kh ? FO_W1B : FO_W1A)) + FI;
        int* fwy0 = (int*)(ws + OFF_FLG + (kh ? FO_WY0B : FO_WY0A)) + FI;
        int* fcons= (int*)(ws + OFF_FLG + (isx0 ? FO_CN0 : FO_CN1)) + FI;

        u16* xst = smem;   // [2 buf][2 plane][16][136] u16 = 8704
        const u16* packW = packs + (isx0 ? PK_WIH0 : (PK_WIH1 + kh * 102400));

        bf16x8 Bx[28];
        #pragma unroll
        for (int s = 0; s < 7; ++s) {
            const int nt = (s < 6) ? (wv + 8 * s) : (48 + wv);
            #pragma unroll
            for (int kt = 0; kt < 4; ++kt)
                if (s < nslot)
                    Bx[s * 4 + kt] = *(const bf16x8*)(packW + ((size_t)(kt * 50 + nt) * 64 + lane) * 8);
        }
        float bias[7];
        #pragma unroll
        for (int s = 0; s < 7; ++s) {
            bias[s] = 0.f;
            if (s < nslot && (isx0 || kh == 0)) {
                const int nt = (s < 6) ? (wv + 8 * s) : (48 + wv);
                const int rp = nt * 16 + lm, g = rp & 3, hc = rp >> 2, R = g * 200 + hc;
                bias[s] = isx0 ? (bf2f(cbf[240000 + R]) + bf2f(cbf[240800 + R]))
                               : (bf2f(cbf[561600 + R]) + bf2f(cbf[562400 + R]));
            }
        }
        // zero both staging buffers fully once (covers k-pad 100..135)
        for (int u = tid; u < 8704; u += 512) xst[u] = 0;

        float2 sreg[2];
        // ---- prologue: stage slot 0 into buf 0 ----
        if (!isx0) { if (tid == 0) spin_ge(fy0p, 1, &budget); }
        __syncthreads();
        #pragma unroll
        for (int j = 0; j < 2; ++j) {
            const int u = tid + 512 * j;
            if (u < 800) {
                const int m = u / 50, k = (u % 50) * 2;
                if (isx0) {
                    const size_t gi = ((size_t)0 * B_ + b0 + m) * IN_ + k;
                    if (isf32) sreg[j] = *(const float2*)((const float*)inp + gi);
                    else { const uint32_t xv = *(const uint32_t*)((const u16*)inp + gi);
                           sreg[j] = make_float2(bf2f((u16)xv), bf2f((u16)(xv >> 16))); }
                } else {
                    sreg[j] = agld2(y0ring + ((size_t)0 * B_ + b0 + m) * H_ + kh * 100 + k);
                }
                const u16 h0 = f2bf(sreg[j].x), h1 = f2bf(sreg[j].y);
                *(uint32_t*)(xst + m * 136 + k) = (uint32_t)h0 | ((uint32_t)h1 << 16);
                *(uint32_t*)(xst + 2176 + m * 136 + k)
                    = (uint32_t)f2bf(sreg[j].x - bf2f(h0)) | ((uint32_t)f2bf(sreg[j].y - bf2f(h1)) << 16);
            }
        }
        __syncthreads();
        int cur = 0;

        for (int t = 0; t < T_; ++t) {
            if (t < T_ - 1) {
                if (tid == 0) {
                    if (!isx0) spin_ge(fy0p, t + 2, &budget);
                    if ((t & 7) == 0) spin_ge(fcons, t - 23, &budget);   // ring space
                }
                __syncthreads();   // SB0: flags visible
                // issue stage loads for t+1 (in flight across GEMM + store window)
                #pragma unroll
                for (int j = 0; j < 2; ++j) {
                    const int u = tid + 512 * j;
                    if (u < 800) {
                        const int m = u / 50, k = (u % 50) * 2;
                        if (isx0) {
                            const size_t gi = ((size_t)(t + 1) * B_ + b0 + m) * IN_ + k;
                            if (isf32) sreg[j] = *(const float2*)((const float*)inp + gi);
                            else { const uint32_t xv = *(const uint32_t*)((const u16*)inp + gi);
                                   sreg[j] = make_float2(bf2f((u16)xv), bf2f((u16)(xv >> 16))); }
                        } else {
                            sreg[j] = agld2(y0ring + ((size_t)((t + 1) & (RDY - 1)) * B_ + b0 + m) * H_ + kh * 100 + k);
                        }
                    }
                }
            }
            // ---- GEMM from xst[cur] ----
            f32x4 acc[7];
            #pragma unroll
            for (int s = 0; s < 7; ++s) {
                acc[s][0] = bias[s]; acc[s][1] = bias[s];
                acc[s][2] = bias[s]; acc[s][3] = bias[s];
            }
            #pragma unroll
            for (int kt = 0; kt < 4; ++kt) {
                const int xa = cur * 4352 + lm * 136 + kt * 32 + 8 * lq;
                const bf16x8 Ahi = *(const bf16x8*)(xst + xa);
                const bf16x8 Alo = *(const bf16x8*)(xst + 2176 + xa);
                #pragma unroll
                for (int s = 0; s < 7; ++s) if (s < nslot) {
                    acc[s] = __builtin_amdgcn_mfma_f32_16x16x32_bf16(Ahi, Bx[s * 4 + kt], acc[s], 0, 0, 0);
                    acc[s] = __builtin_amdgcn_mfma_f32_16x16x32_bf16(Alo, Bx[s * 4 + kt], acc[s], 0, 0, 0);
                }
            }
            // ---- emit partials to ring slot t ----
            float* ring = (isx0 ? pr0 : (kh ? pr1b : pr1a))
                        + (size_t)((t & (RD - 1)) * 8 + i) * 12800;
            #pragma unroll
            for (int s = 0; s < 7; ++s) if (s < nslot) {
                const int nt = (s < 6) ? (wv + 8 * s) : (48 + wv);
                float* pp = ring + nt * 256 + lane * 4;
                agst2(pp, acc[s][0], acc[s][1]);
                agst2(pp + 2, acc[s][2], acc[s][3]);
            }
            __syncthreads();   // SB2: drains stage loads (t+1) AND ring stores (t)
            if (tid == 0) {
                if (isx0) { if (((t + 1) & 3) == 0) agsti(fx0p, t + 1); }
                else      { agsti(fw1, t + 1); agsti(fwy0, t + 1); }
            }
            if (t < T_ - 1) {
                // write staged regs -> LDS buf cur^1 (hi/lo bf16)
                const int nb = (cur ^ 1) * 4352;
                #pragma unroll
                for (int j = 0; j < 2; ++j) {
                    const int u = tid + 512 * j;
                    if (u < 800) {
                        const int m = u / 50, k = (u % 50) * 2;
                        const u16 h0 = f2bf(sreg[j].x), h1 = f2bf(sreg[j].y);
                        *(uint32_t*)(xst + nb + m * 136 + k) = (uint32_t)h0 | ((uint32_t)h1 << 16);
                        *(uint32_t*)(xst + nb + 2176 + m * 136 + k)
                            = (uint32_t)f2bf(sreg[j].x - bf2f(h0)) | ((uint32_t)f2bf(sreg[j].y - bf2f(h1)) << 16);
                    }
                }
                __syncthreads();   // SB3: staging visible for next GEMM
                cur ^= 1;
            }
        }
    }
}

// out[m][c] = sum_k y1[m][k] * fcW[c][k] + fcb[c]
__launch_bounds__(256)
__global__ void fc_kernel(const u16* __restrict__ y1, const u16* __restrict__ cbf,
                          const int* __restrict__ flag, void* __restrict__ out)
{
    __shared__ float y1s[16 * 201];
    const int isf32 = *flag;
    const u16* fcW = cbf + 563200;
    const u16* fcb = cbf + 583200;
    const int tid = threadIdx.x;
    const int m0 = blockIdx.x * 16;
    for (int idx = tid; idx < 16 * 200; idx += 256) {
        int r = idx / 200, k = idx % 200;
        y1s[r * 201 + k] = bf2f(y1[(size_t)(m0 + r) * 200 + k]);
    }
    __syncthreads();
    const int r = tid & 15, ct = tid >> 4;
    float acc[7] = {0.f, 0.f, 0.f, 0.f, 0.f, 0.f, 0.f};
    for (int k = 0; k < 200; ++k) {
        const float x = y1s[r * 201 + k];
        #pragma unroll
        for (int qn = 0; qn < 7; ++qn) {
            int cc = ct + 16 * qn;
            if (cc < 100) acc[qn] = fmaf(x, bf2f(fcW[cc * 200 + k]), acc[qn]);
        }
    }
    #pragma unroll
    for (int qn = 0; qn < 7; ++qn) {
        int cc = ct + 16 * qn;
        if (cc < 100) {
            float v = acc[qn] + bf2f(fcb[cc]);
            v = (v == v) ? v : 0.f;
            const size_t oi = (size_t)(m0 + r) * 100 + cc;
            if (isf32) ((float*)out)[oi] = v;
            else       ((u16*)out)[oi] = f2bf(v);
        }
    }
}

extern "C" void kernel_launch(void* const* d_in, const int* in_sizes, int n_in,
                              void* d_out, int out_size, void* d_ws, size_t ws_size,
                              hipStream_t stream)
{
    const void* inp  = d_in[0];
    const void* h0   = d_in[1];
    const void* c0   = d_in[2];
    const void* Wih0 = d_in[3];
    const void* Whh0 = d_in[4];
    const void* bih0 = d_in[5];
    const void* bhh0 = d_in[6];
    const void* Wih1 = d_in[7];
    const void* Whh1 = d_in[8];
    const void* bih1 = d_in[9];
    const void* bhh1 = d_in[10];
    const void* fcW  = d_in[11];
    const void* fcb  = d_in[12];

    if (ws_size < WS_NEEDED) return;   // fail visibly rather than corrupt

    char* ws = (char*)d_ws;
    u16*   cbf  = (u16*)(ws + OFF_CBF);
    float* ch0  = (float*)(ws + OFF_CH0);
    float* cc0  = (float*)(ws + OFF_CC0);
    u16*   pw   = (u16*)(ws + OFF_PACK);
    int*   dflag= (int*)(ws + OFF_FLG + FO_DTF);
    u16*   y1buf= (u16*)(ws + OFF_Y1);

    // zero only the flag/watermark region (rings are flag-gated)
    hipMemsetAsync(ws + OFF_FLG, 0, 4160, stream);

    detect_kernel<<<1, 256, 0, stream>>>(Wih0, dflag);
    prep_kernel<<<512, 256, 0, stream>>>(Wih0, Whh0, bih0, bhh0,
                                         Wih1, Whh1, bih1, bhh1,
                                         fcW, fcb, h0, c0, cbf, ch0, cc0, dflag);
    pack_kernel<<<256, 256, 0, stream>>>(cbf, pw);
    lstm_pipe<<<40, 512, 0, stream>>>(inp, ws, dflag, d_out);
    fc_kernel<<<8192, 256, 0, stream>>>(y1buf, cbf, dflag, d_out);
}

// Round 9
// 6453.349 us; speedup vs baseline: 1.9539x; 1.0031x over previous
//
#include <hip/hip_runtime.h>
#include <stdint.h>

#define T_ 1024
#define B_ 128
#define IN_ 100
#define H_ 200
#define RD 32      // pr ring depth (power of 2)
#define RDY 32     // y0 ring depth (power of 2)

typedef unsigned short u16;
typedef unsigned long long u64;
typedef short bf16x8 __attribute__((ext_vector_type(8)));
typedef float f32x4  __attribute__((ext_vector_type(4)));

// ---------------- workspace layout (bytes) ----------------
#define OFF_Y1    0u            // u16 [1024][128][200]        52,428,800
#define OFF_Y0R   52428800u     // f32 [32][128][200]           3,276,800
#define OFF_PR0   55705600u     // f32 [32][8][12800]          13,107,200
#define OFF_PR1A  68812800u     // f32 [32][8][12800]          13,107,200
#define OFF_PR1B  81920000u     // f32 [32][8][12800]          13,107,200
#define OFF_PACK  95027200u     // u16 packs 665,600            1,331,200
#define OFF_CBF   96358400u     // u16 canonical [583300]       1,166,656
#define OFF_CH0   97525056u     // f32 [2][128][200]              204,800
#define OFF_CC0   97729856u     // f32 [2][128][200]              204,800
#define OFF_FLG   97934656u     // watermark arrays + dtype flag    4,160
#define WS_NEEDED 97938816u
// flag sub-offsets (bytes from OFF_FLG); each array int[8] strided 16 ints
#define FO_X0P  0u       // x0 produced watermark (posted every 4)
#define FO_Y0P  512u     // L0 h produced watermark (every step)
#define FO_W1A  1024u    // x1 kh0 ring produced watermark
#define FO_W1B  1536u    // x1 kh1 ring produced watermark
#define FO_WY0A 2048u    // x1 kh0 y0-staged watermark
#define FO_WY0B 2560u    // x1 kh1 y0-staged watermark
#define FO_CN0  3072u    // L0 pr0 consumed watermark (every 8)
#define FO_CN1  3584u    // L1 pr1 consumed watermark (every 8)
#define FO_DTF  4096u    // dtype flag
// pack sub-offsets in u16 units relative to OFF_PACK (all bf16)
#define PK_WHH0 0
#define PK_WHH1 179200
#define PK_WIH0 358400
#define PK_WIH1 460800

__device__ __forceinline__ float bf2f(u16 u) {
    union { uint32_t i; float f; } v; v.i = ((uint32_t)u) << 16; return v.f;
}
__device__ __forceinline__ u16 f2bf(float f) {
    union { uint32_t i; float f; } v; v.f = f;
    uint32_t x = v.i;
    x += 0x7fff + ((x >> 16) & 1);
    return (u16)(x >> 16);
}
// 8-byte agent-scope relaxed payload movement (IC-coherent, 2 floats/op)
__device__ __forceinline__ void agst2(float* p, float a, float b) {
    union { u64 u; float f[2]; } v; v.f[0] = a; v.f[1] = b;
    __hip_atomic_store((u64*)p, v.u, __ATOMIC_RELAXED, __HIP_MEMORY_SCOPE_AGENT);
}
__device__ __forceinline__ float2 agld2(const float* p) {
    union { u64 u; float f[2]; } v;
    v.u = __hip_atomic_load((u64*)p, __ATOMIC_RELAXED, __HIP_MEMORY_SCOPE_AGENT);
    return make_float2(v.f[0], v.f[1]);
}
__device__ __forceinline__ void agsti(int* p, int v) {
    __hip_atomic_store(p, v, __ATOMIC_RELAXED, __HIP_MEMORY_SCOPE_AGENT);
}
__device__ __forceinline__ void spin_ge(int* p, int val, int* budget) {
    while (__hip_atomic_load(p, __ATOMIC_RELAXED, __HIP_MEMORY_SCOPE_AGENT) < val) {
        __builtin_amdgcn_s_sleep(1);
        if (--(*budget) < 0) return;
    }
}
// fast activations (error ~1e-6, far inside tolerance)
__device__ __forceinline__ float fsig(float x) {
    const float e = __expf(-x);
    return __builtin_amdgcn_rcpf(1.f + e);
}
__device__ __forceinline__ float ftanh(float x) {
    const float ax = __builtin_fabsf(x);
    const float e = __expf(-2.f * ax);
    const float r = (1.f - e) * __builtin_amdgcn_rcpf(1.f + e);
    return __builtin_copysignf(r, x);
}

// ---------- dtype detector ----------
__global__ void detect_kernel(const void* w, int* flag) {
    __shared__ int cnt;
    if (threadIdx.x == 0) cnt = 0;
    __syncthreads();
    const u16* p = (const u16*)w;
    int bad = 0;
    for (int e = 0; e < 16; ++e) {
        u16 u = p[threadIdx.x * 16 + e];
        int ex = (u >> 7) & 0xFF;
        float v = bf2f(u);
        float av = v < 0.f ? -v : v;
        if (ex == 0xFF || av > 0.5f) bad++;
    }
    atomicAdd(&cnt, bad);
    __syncthreads();
    if (threadIdx.x == 0) flag[0] = (cnt > 64) ? 1 : 0;
}

// ---------- canonicalize params ----------
__global__ void prep_kernel(const void* Wih0, const void* Whh0,
                            const void* bih0, const void* bhh0,
                            const void* Wih1, const void* Whh1,
                            const void* bih1, const void* bhh1,
                            const void* fcW,  const void* fcb,
                            const void* h0,   const void* c0,
                            u16* cbf, float* ch0, float* cc0, const int* flag)
{
    const int isf32 = *flag;
    const int N = 685700;
    for (int idx = blockIdx.x * 256 + threadIdx.x; idx < N; idx += gridDim.x * 256) {
        const void* src; int e = idx; u16* du = nullptr; float* df = nullptr;
        if (e < 80000)                 { src = Wih0; du = cbf; }
        else if ((e -= 80000) < 160000){ src = Whh0; du = cbf + 80000; }
        else if ((e -= 160000) < 800)  { src = bih0; du = cbf + 240000; }
        else if ((e -= 800) < 800)     { src = bhh0; du = cbf + 240800; }
        else if ((e -= 800) < 160000)  { src = Wih1; du = cbf + 241600; }
        else if ((e -= 160000) < 160000){ src = Whh1; du = cbf + 401600; }
        else if ((e -= 160000) < 800)  { src = bih1; du = cbf + 561600; }
        else if ((e -= 800) < 800)     { src = bhh1; du = cbf + 562400; }
        else if ((e -= 800) < 20000)   { src = fcW;  du = cbf + 563200; }
        else if ((e -= 20000) < 100)   { src = fcb;  du = cbf + 583200; }
        else if ((e -= 100) < 51200)   { src = h0;   df = ch0; }
        else         { e -= 51200;       src = c0;   df = cc0; }
        float v = isf32 ? ((const float*)src)[e] : bf2f(((const u16*)src)[e]);
        if (du) du[e] = f2bf(v); else df[e] = v;
    }
}

// ---------- pack weights into MFMA B-fragment order (all bf16) ----------
// r' = hc*4 + g. tile (kt,nt): lane l, elem e holds
// W[r' = nt*16+(l&15)][k = kt*32 + (l>>4)*8 + e]  (k-pad -> 0)
__global__ void pack_kernel(const u16* __restrict__ cbf, u16* __restrict__ pw) {
    const int N = 665600;
    for (int idx = blockIdx.x * 256 + threadIdx.x; idx < N; idx += gridDim.x * 256) {
        int e = idx; const u16* src; int ld, koff, kmax, rel;
        if (e < 179200)                    { rel = e; src = cbf + 80000;  ld = 200; kmax = 200; koff = 0; }
        else if ((e -= 179200) < 179200)   { rel = e; src = cbf + 401600; ld = 200; kmax = 200; koff = 0; }
        else if ((e -= 179200) < 102400)   { rel = e; src = cbf + 0;      ld = 100; kmax = 100; koff = 0; }
        else { e -= 102400; const int kh = e / 102400; rel = e % 102400;
               src = cbf + 241600; ld = 200; kmax = 100; koff = kh * 100; }
        const int el = rel & 7, l = (rel >> 3) & 63, tile = rel >> 9;
        const int nt = tile % 50, kt = tile / 50;
        const int rp = nt * 16 + (l & 15), g = rp & 3, hc = rp >> 2;
        const int k = kt * 32 + ((l >> 4) << 3) + el;
        u16 v = 0;
        if (k < kmax) v = src[(g * 200 + hc) * ld + koff + k];
        pw[idx] = v;
    }
}

// ============================================================
// 40 persistent blocks x 512 threads (1 block/CU; 8 waves).
// EXACT round-4 structure_A' — VERIFIED PASSING (absmax 0.0039, 6.47 ms).
// Structure_B (SB3 removed + batched fy0p) failed 4/4 across numeric
// configs incl. byte-identical numerics => racy; SB3 and the per-step
// fy0p spin are LOAD-BEARING. Do not remove.
//   bid 0-15 : cell blocks (L, i): block-private recurrence, W_hh resident
//              bf16 fragments, h as HI/LO bf16 planes (hi/lo REQUIRED:
//              single-plane h fails; fp16 planes fail via denormal flush).
//   bid 16-23: x0 blocks: inp @ W_ih0^T + biases -> pr0 ring (depth 32).
//   bid 24-39: x1 blocks (i,kh): y0 @ W_ih1^T half-K -> pr1a/pr1b,
//              double-buffered LDS staging, SB0/SB2/SB3 barriers.
// ============================================================
__launch_bounds__(512, 1)
__global__ void lstm_pipe(const void* __restrict__ inp, char* __restrict__ ws,
                          const int* __restrict__ flag, void* __restrict__ out)
{
    __shared__ __align__(16) u16 smem[67392];   // 134,784 B

    u16*   y1buf  = (u16*)(ws + OFF_Y1);
    float* y0ring = (float*)(ws + OFF_Y0R);
    float* pr0    = (float*)(ws + OFF_PR0);
    float* pr1a   = (float*)(ws + OFF_PR1A);
    float* pr1b   = (float*)(ws + OFF_PR1B);
    u16*   packs  = (u16*)(ws + OFF_PACK);
    const u16* cbf = (const u16*)(ws + OFF_CBF);
    const float* ch0 = (const float*)(ws + OFF_CH0);
    const float* cc0 = (const float*)(ws + OFF_CC0);

    const int isf32 = *flag;
    const int tid = threadIdx.x;
    const int bid = blockIdx.x;
    const int lane = tid & 63, wv = tid >> 6;
    const int lm = lane & 15, lq = lane >> 4;
    const int nslot = (wv < 2) ? 7 : 6;   // 50 N-tiles over 8 waves
    int budget = 1 << 22;

    if (bid < 16) {
        // ======================= CELL =======================
        const int L = bid >> 3, i = bid & 7, b0 = i * 16;
        const int FI = i * 16;
        int* fx0p = (int*)(ws + OFF_FLG + FO_X0P) + FI;
        int* fw1a = (int*)(ws + OFF_FLG + FO_W1A) + FI;
        int* fw1b = (int*)(ws + OFF_FLG + FO_W1B) + FI;
        int* fwy0a= (int*)(ws + OFF_FLG + FO_WY0A) + FI;
        int* fwy0b= (int*)(ws + OFF_FLG + FO_WY0B) + FI;
        int* fy0p = (int*)(ws + OFF_FLG + FO_Y0P) + FI;
        int* fcn0 = (int*)(ws + OFF_FLG + FO_CN0) + FI;
        int* fcn1 = (int*)(ws + OFF_FLG + FO_CN1) + FI;

        u16* ldsB = smem;                               // 62 tiles * 512 u16
        u16* hls  = smem + 31744;                       // [2][16][264] bf16 hi/lo
        float* gls = (float*)(smem + 40192);            // [4][200][17] f32
        const u16* packW = packs + (L ? PK_WHH1 : PK_WHH0);

        // --- persistent VGPR B tiles: slots 0-4 all kt, slot5 kt0 ---
        bf16x8 Bv[36];
        #pragma unroll
        for (int s = 0; s < 7; ++s) {
            const int nt = (s < 6) ? (wv + 8 * s) : (48 + wv);
            #pragma unroll
            for (int kt = 0; kt < 7; ++kt) {
                if (s < 5) {
                    Bv[s * 7 + kt] = *(const bf16x8*)(packW + ((size_t)(kt * 50 + nt) * 64 + lane) * 8);
                } else if (s == 5 && kt == 0) {
                    Bv[35] = *(const bf16x8*)(packW + ((size_t)(kt * 50 + nt) * 64 + lane) * 8);
                }
            }
        }
        // --- LDS B tiles: slot5 kt1-6 (all waves) + slot6 kt0-6 (waves 0,1) ---
        for (int u = tid; u < 31744; u += 512) {
            const int eidx = u >> 9, off = u & 511;
            int kt, nt;
            if (eidx < 48) { kt = 1 + eidx % 6; nt = (eidx / 6) + 40; }
            else { const int e2 = eidx - 48; kt = e2 % 7; nt = 48 + e2 / 7; }
            ldsB[u] = packW[(size_t)(kt * 50 + nt) * 512 + off];
        }
        // --- h(-1) hi/lo bf16 planes (+ zero k-pad) ---
        for (int u = tid; u < 2 * 16 * 264; u += 512) {
            const int pl = u / (16 * 264), m = (u / 264) % 16, k = u % 264;
            u16 v = 0;
            if (k < 200) {
                const float h = ch0[L * B_ * H_ + (b0 + m) * H_ + k];
                const u16 hi = f2bf(h);
                v = pl ? f2bf(h - bf2f(hi)) : hi;
            }
            hls[u] = v;
        }
        // --- c state: thread owns PAIRS p = tid + 512*k4 -> (m, hc=2*(p%100)) ---
        float c2[4][2];
        #pragma unroll
        for (int k4 = 0; k4 < 4; ++k4) {
            const int p = tid + 512 * k4;
            c2[k4][0] = 0.f; c2[k4][1] = 0.f;
            if (p < 1600) {
                const int m = p / 100, hc = (p % 100) * 2;
                c2[k4][0] = cc0[L * B_ * H_ + (b0 + m) * H_ + hc];
                c2[k4][1] = cc0[L * B_ * H_ + (b0 + m) * H_ + hc + 1];
            }
        }
        // --- prologue: wait slot 0 available, prefetch into acc ---
        f32x4 acc[7];
        if (tid == 0) {
            if (L == 0) spin_ge(fx0p, 1, &budget);
            else        { spin_ge(fw1a, 1, &budget); spin_ge(fw1b, 1, &budget); }
        }
        __syncthreads();
        {
            const size_t roff = (size_t)(0 * 8 + i) * 12800;
            #pragma unroll
            for (int s = 0; s < 7; ++s) if (s < nslot) {
                const int nt = (s < 6) ? (wv + 8 * s) : (48 + wv);
                float* pa = ((L ? pr1a : pr0) + roff) + nt * 256 + lane * 4;
                const float2 a01 = agld2(pa);
                const float2 a23 = agld2(pa + 2);
                acc[s][0] = a01.x; acc[s][1] = a01.y;
                acc[s][2] = a23.x; acc[s][3] = a23.y;
                if (L) {
                    float* pb = (pr1b + roff) + nt * 256 + lane * 4;
                    const float2 b01 = agld2(pb);
                    const float2 b23 = agld2(pb + 2);
                    acc[s][0] += b01.x; acc[s][1] += b01.y;
                    acc[s][2] += b23.x; acc[s][3] += b23.y;
                }
            }
        }
        __syncthreads();

        for (int t = 0; t < T_; ++t) {
            // ---- phase 1: h-GEMM (hi+lo bf16 planes), weights resident ----
            #pragma unroll
            for (int kt = 0; kt < 7; ++kt) {
                const int ha = lm * 264 + kt * 32 + 8 * lq;
                const bf16x8 Ahi = *(const bf16x8*)(hls + ha);
                const bf16x8 Alo = *(const bf16x8*)(hls + 16 * 264 + ha);
                #pragma unroll
                for (int s = 0; s < 7; ++s) if (s < nslot) {
                    bf16x8 Bt;
                    if (s < 5)                 Bt = Bv[s * 7 + kt];
                    else if (s == 5 && kt == 0) Bt = Bv[35];
                    else {
                        const int eidx = (s == 5) ? (wv * 6 + kt - 1) : (48 + wv * 7 + kt);
                        Bt = *(const bf16x8*)(ldsB + eidx * 512 + lane * 8);
                    }
                    acc[s] = __builtin_amdgcn_mfma_f32_16x16x32_bf16(Ahi, Bt, acc[s], 0, 0, 0);
                    acc[s] = __builtin_amdgcn_mfma_f32_16x16x32_bf16(Alo, Bt, acc[s], 0, 0, 0);
                }
            }
            // ---- phase 2: gates -> LDS ([g][hc][m], stride 17) ----
            #pragma unroll
            for (int s = 0; s < 7; ++s) if (s < nslot) {
                const int nt = (s < 6) ? (wv + 8 * s) : (48 + wv);
                const int g = lm & 3, hc = nt * 4 + (lm >> 2);
                float* gp = gls + g * 3400 + hc * 17 + 4 * lq;
                gp[0] = acc[s][0]; gp[1] = acc[s][1]; gp[2] = acc[s][2]; gp[3] = acc[s][3];
            }
            __syncthreads();   // B1: gates visible
            // ---- batched flag window (every 8 steps only) ----
            if ((t & 7) == 0) {
                if (tid == 0) {
                    int tgt = t + 9; if (tgt > T_) tgt = T_;
                    if (L == 0) {
                        spin_ge(fx0p, tgt, &budget);
                        spin_ge(fwy0a, t - 15, &budget);   // y0ring reuse safety
                        spin_ge(fwy0b, t - 15, &budget);
                    } else {
                        spin_ge(fw1a, tgt, &budget);
                        spin_ge(fw1b, tgt, &budget);
                    }
                }
                __syncthreads();   // B1b (only on checked steps)
            }
            // ---- prefetch ring slot t+1 into acc (flag guaranteed by batch) ----
            if (t < T_ - 1) {
                const size_t roff = (size_t)(((t + 1) & (RD - 1)) * 8 + i) * 12800;
                #pragma unroll
                for (int s = 0; s < 7; ++s) if (s < nslot) {
                    const int nt = (s < 6) ? (wv + 8 * s) : (48 + wv);
                    float* pa = ((L ? pr1a : pr0) + roff) + nt * 256 + lane * 4;
                    const float2 a01 = agld2(pa);
                    const float2 a23 = agld2(pa + 2);
                    acc[s][0] = a01.x; acc[s][1] = a01.y;
                    acc[s][2] = a23.x; acc[s][3] = a23.y;
                    if (L) {
                        float* pb = (pr1b + roff) + nt * 256 + lane * 4;
                        const float2 b01 = agld2(pb);
                        const float2 b23 = agld2(pb + 2);
                        acc[s][0] += b01.x; acc[s][1] += b01.y;
                        acc[s][2] += b23.x; acc[s][3] += b23.y;
                    }
                }
            }
            // ---- pointwise LSTM cell: thread owns 2 adjacent hc ----
            #pragma unroll
            for (int k4 = 0; k4 < 4; ++k4) {
                const int p = tid + 512 * k4;
                if (p < 1600) {
                    const int m = p / 100, hc = (p % 100) * 2;
                    float ig0 = gls[hc * 17 + m],        ig1 = gls[(hc + 1) * 17 + m];
                    float fg0 = gls[3400 + hc * 17 + m], fg1 = gls[3400 + (hc + 1) * 17 + m];
                    float gg0 = gls[6800 + hc * 17 + m], gg1 = gls[6800 + (hc + 1) * 17 + m];
                    float og0 = gls[10200 + hc * 17 + m],og1 = gls[10200 + (hc + 1) * 17 + m];
                    ig0 = (ig0 == ig0) ? ig0 : 0.f;  ig1 = (ig1 == ig1) ? ig1 : 0.f;
                    fg0 = (fg0 == fg0) ? fg0 : 0.f;  fg1 = (fg1 == fg1) ? fg1 : 0.f;
                    gg0 = (gg0 == gg0) ? gg0 : 0.f;  gg1 = (gg1 == gg1) ? gg1 : 0.f;
                    og0 = (og0 == og0) ? og0 : 0.f;  og1 = (og1 == og1) ? og1 : 0.f;
                    ig0 = fsig(ig0); ig1 = fsig(ig1);
                    fg0 = fsig(fg0); fg1 = fsig(fg1);
                    og0 = fsig(og0); og1 = fsig(og1);
                    gg0 = ftanh(gg0); gg1 = ftanh(gg1);
                    c2[k4][0] = fg0 * c2[k4][0] + ig0 * gg0;
                    c2[k4][1] = fg1 * c2[k4][1] + ig1 * gg1;
                    const float h0v = og0 * ftanh(c2[k4][0]);
                    const float h1v = og1 * ftanh(c2[k4][1]);
                    const u16 hi0 = f2bf(h0v), hi1 = f2bf(h1v);
                    const u16 lo0 = f2bf(h0v - bf2f(hi0)), lo1 = f2bf(h1v - bf2f(hi1));
                    *(uint32_t*)(hls + m * 264 + hc) = (uint32_t)hi0 | ((uint32_t)hi1 << 16);
                    *(uint32_t*)(hls + (16 + m) * 264 + hc) = (uint32_t)lo0 | ((uint32_t)lo1 << 16);
                    if (L == 0) {
                        agst2(y0ring + ((size_t)(t & (RDY - 1)) * B_ + b0 + m) * H_ + hc, h0v, h1v);
                    } else {
                        *(uint32_t*)(y1buf + ((size_t)t * B_ + b0 + m) * H_ + hc)
                            = (uint32_t)hi0 | ((uint32_t)hi1 << 16);
                    }
                    if (t == T_ - 1) {
                        const size_t base = (size_t)T_ * B_ * IN_;
                        const size_t bb = (size_t)(b0 + m) * H_ + hc;
                        const size_t o1 = base + (size_t)L * B_ * H_ + bb;
                        const size_t o2 = base + 2 * (size_t)B_ * H_ + (size_t)L * B_ * H_ + bb;
                        if (isf32) {
                            ((float*)out)[o1] = h0v; ((float*)out)[o1 + 1] = h1v;
                            ((float*)out)[o2] = c2[k4][0]; ((float*)out)[o2 + 1] = c2[k4][1];
                        } else {
                            ((u16*)out)[o1] = hi0; ((u16*)out)[o1 + 1] = hi1;
                            ((u16*)out)[o2] = f2bf(c2[k4][0]); ((u16*)out)[o2 + 1] = f2bf(c2[k4][1]);
                        }
                    }
                }
            }
            __syncthreads();   // B2: h(t) consumed; prefetch loads + y0 stores drained
            if (tid == 0) {
                if (L == 0) {
                    agsti(fy0p, t + 1);
                    if (((t + 1) & 7) == 0) agsti(fcn0, t + 1);
                } else {
                    if (((t + 1) & 7) == 0) agsti(fcn1, t + 1);
                }
            }
        }
    } else {
        // ======================= X BLOCKS =======================
        const int isx0 = (bid < 24);
        const int i  = isx0 ? (bid - 16) : ((bid - 24) >> 1);
        const int kh = isx0 ? 0 : ((bid - 24) & 1);
        const int b0 = i * 16;
        const int FI = i * 16;
        int* fx0p = (int*)(ws + OFF_FLG + FO_X0P) + FI;
        int* fy0p = (int*)(ws + OFF_FLG + FO_Y0P) + FI;
        int* fw1  = (int*)(ws + OFF_FLG + (kh ? FO_W1B : FO_W1A)) + FI;
        int* fwy0 = (int*)(ws + OFF_FLG + (kh ? FO_WY0B : FO_WY0A)) + FI;
        int* fcons= (int*)(ws + OFF_FLG + (isx0 ? FO_CN0 : FO_CN1)) + FI;

        u16* xst = smem;   // [2 buf][2 plane][16][136] u16 = 8704
        const u16* packW = packs + (isx0 ? PK_WIH0 : (PK_WIH1 + kh * 102400));

        bf16x8 Bx[28];
        #pragma unroll
        for (int s = 0; s < 7; ++s) {
            const int nt = (s < 6) ? (wv + 8 * s) : (48 + wv);
            #pragma unroll
            for (int kt = 0; kt < 4; ++kt)
                if (s < nslot)
                    Bx[s * 4 + kt] = *(const bf16x8*)(packW + ((size_t)(kt * 50 + nt) * 64 + lane) * 8);
        }
        float bias[7];
        #pragma unroll
        for (int s = 0; s < 7; ++s) {
            bias[s] = 0.f;
            if (s < nslot && (isx0 || kh == 0)) {
                const int nt = (s < 6) ? (wv + 8 * s) : (48 + wv);
                const int rp = nt * 16 + lm, g = rp & 3, hc = rp >> 2, R = g * 200 + hc;
                bias[s] = isx0 ? (bf2f(cbf[240000 + R]) + bf2f(cbf[240800 + R]))
                               : (bf2f(cbf[561600 + R]) + bf2f(cbf[562400 + R]));
            }
        }
        // zero both staging buffers fully once (covers k-pad 100..135)
        for (int u = tid; u < 8704; u += 512) xst[u] = 0;

        float2 sreg[2];
        // ---- prologue: stage slot 0 into buf 0 ----
        if (!isx0) { if (tid == 0) spin_ge(fy0p, 1, &budget); }
        __syncthreads();
        #pragma unroll
        for (int j = 0; j < 2; ++j) {
            const int u = tid + 512 * j;
            if (u < 800) {
                const int m = u / 50, k = (u % 50) * 2;
                if (isx0) {
                    const size_t gi = ((size_t)0 * B_ + b0 + m) * IN_ + k;
                    if (isf32) sreg[j] = *(const float2*)((const float*)inp + gi);
                    else { const uint32_t xv = *(const uint32_t*)((const u16*)inp + gi);
                           sreg[j] = make_float2(bf2f((u16)xv), bf2f((u16)(xv >> 16))); }
                } else {
                    sreg[j] = agld2(y0ring + ((size_t)0 * B_ + b0 + m) * H_ + kh * 100 + k);
                }
                const u16 h0 = f2bf(sreg[j].x), h1 = f2bf(sreg[j].y);
                *(uint32_t*)(xst + m * 136 + k) = (uint32_t)h0 | ((uint32_t)h1 << 16);
                *(uint32_t*)(xst + 2176 + m * 136 + k)
                    = (uint32_t)f2bf(sreg[j].x - bf2f(h0)) | ((uint32_t)f2bf(sreg[j].y - bf2f(h1)) << 16);
            }
        }
        __syncthreads();
        int cur = 0;

        for (int t = 0; t < T_; ++t) {
            if (t < T_ - 1) {
                if (tid == 0) {
                    if (isx0) {
                        if ((t & 7) == 0) spin_ge(fcons, t - 23, &budget);   // ring space
                    } else {
                        spin_ge(fy0p, t + 2, &budget);                       // y0 available
                        if ((t & 7) == 0) spin_ge(fcons, t - 23, &budget);   // ring space
                    }
                }
                __syncthreads();   // SB0: flags observed
                // issue stage loads for t+1 (in flight across GEMM + store window)
                #pragma unroll
                for (int j = 0; j < 2; ++j) {
                    const int u = tid + 512 * j;
                    if (u < 800) {
                        const int m = u / 50, k = (u % 50) * 2;
                        if (isx0) {
                            const size_t gi = ((size_t)(t + 1) * B_ + b0 + m) * IN_ + k;
                            if (isf32) sreg[j] = *(const float2*)((const float*)inp + gi);
                            else { const uint32_t xv = *(const uint32_t*)((const u16*)inp + gi);
                                   sreg[j] = make_float2(bf2f((u16)xv), bf2f((u16)(xv >> 16))); }
                        } else {
                            sreg[j] = agld2(y0ring + ((size_t)((t + 1) & (RDY - 1)) * B_ + b0 + m) * H_ + kh * 100 + k);
                        }
                    }
                }
            }
            // ---- GEMM from xst[cur] ----
            f32x4 acc[7];
            #pragma unroll
            for (int s = 0; s < 7; ++s) {
                acc[s][0] = bias[s]; acc[s][1] = bias[s];
                acc[s][2] = bias[s]; acc[s][3] = bias[s];
            }
            #pragma unroll
            for (int kt = 0; kt < 4; ++kt) {
                const int xa = cur * 4352 + lm * 136 + kt * 32 + 8 * lq;
                const bf16x8 Ahi = *(const bf16x8*)(xst + xa);
                const bf16x8 Alo = *(const bf16x8*)(xst + 2176 + xa);
                #pragma unroll
                for (int s = 0; s < 7; ++s) if (s < nslot) {
                    acc[s] = __builtin_amdgcn_mfma_f32_16x16x32_bf16(Ahi, Bx[s * 4 + kt], acc[s], 0, 0, 0);
                    acc[s] = __builtin_amdgcn_mfma_f32_16x16x32_bf16(Alo, Bx[s * 4 + kt], acc[s], 0, 0, 0);
                }
            }
            // ---- emit partials to ring slot t ----
            float* ring = (isx0 ? pr0 : (kh ? pr1b : pr1a))
                        + (size_t)((t & (RD - 1)) * 8 + i) * 12800;
            #pragma unroll
            for (int s = 0; s < 7; ++s) if (s < nslot) {
                const int nt = (s < 6) ? (wv + 8 * s) : (48 + wv);
                float* pp = ring + nt * 256 + lane * 4;
                agst2(pp, acc[s][0], acc[s][1]);
                agst2(pp + 2, acc[s][2], acc[s][3]);
            }
            __syncthreads();   // SB2: drains stage loads (t+1) AND ring stores (t)
            if (tid == 0) {
                if (isx0) { if (((t + 1) & 3) == 0) agsti(fx0p, t + 1); }
                else      { agsti(fw1, t + 1); agsti(fwy0, t + 1); }
            }
            if (t < T_ - 1) {
                // write staged regs -> LDS buf cur^1 (hi/lo bf16)
                const int nb = (cur ^ 1) * 4352;
                #pragma unroll
                for (int j = 0; j < 2; ++j) {
                    const int u = tid + 512 * j;
                    if (u < 800) {
                        const int m = u / 50, k = (u % 50) * 2;
                        const u16 h0 = f2bf(sreg[j].x), h1 = f2bf(sreg[j].y);
                        *(uint32_t*)(xst + nb + m * 136 + k) = (uint32_t)h0 | ((uint32_t)h1 << 16);
                        *(uint32_t*)(xst + nb + 2176 + m * 136 + k)
                            = (uint32_t)f2bf(sreg[j].x - bf2f(h0)) | ((uint32_t)f2bf(sreg[j].y - bf2f(h1)) << 16);
                    }
                }
                __syncthreads();   // SB3: staging visible for next GEMM (LOAD-BEARING)
                cur ^= 1;
            }
        }
    }
}

// out[m][c] = sum_k y1[m][k] * fcW[c][k] + fcb[c]
__launch_bounds__(256)
__global__ void fc_kernel(const u16* __restrict__ y1, const u16* __restrict__ cbf,
                          const int* __restrict__ flag, void* __restrict__ out)
{
    __shared__ float y1s[16 * 201];
    const int isf32 = *flag;
    const u16* fcW = cbf + 563200;
    const u16* fcb = cbf + 583200;
    const int tid = threadIdx.x;
    const int m0 = blockIdx.x * 16;
    for (int idx = tid; idx < 16 * 200; idx += 256) {
        int r = idx / 200, k = idx % 200;
        y1s[r * 201 + k] = bf2f(y1[(size_t)(m0 + r) * 200 + k]);
    }
    __syncthreads();
    const int r = tid & 15, ct = tid >> 4;
    float acc[7] = {0.f, 0.f, 0.f, 0.f, 0.f, 0.f, 0.f};
    for (int k = 0; k < 200; ++k) {
        const float x = y1s[r * 201 + k];
        #pragma unroll
        for (int qn = 0; qn < 7; ++qn) {
            int cc = ct + 16 * qn;
            if (cc < 100) acc[qn] = fmaf(x, bf2f(fcW[cc * 200 + k]), acc[qn]);
        }
    }
    #pragma unroll
    for (int qn = 0; qn < 7; ++qn) {
        int cc = ct + 16 * qn;
        if (cc < 100) {
            float v = acc[qn] + bf2f(fcb[cc]);
            v = (v == v) ? v : 0.f;
            const size_t oi = (size_t)(m0 + r) * 100 + cc;
            if (isf32) ((float*)out)[oi] = v;
            else       ((u16*)out)[oi] = f2bf(v);
        }
    }
}

extern "C" void kernel_launch(void* const* d_in, const int* in_sizes, int n_in,
                              void* d_out, int out_size, void* d_ws, size_t ws_size,
                              hipStream_t stream)
{
    const void* inp  = d_in[0];
    const void* h0   = d_in[1];
    const void* c0   = d_in[2];
    const void* Wih0 = d_in[3];
    const void* Whh0 = d_in[4];
    const void* bih0 = d_in[5];
    const void* bhh0 = d_in[6];
    const void* Wih1 = d_in[7];
    const void* Whh1 = d_in[8];
    const void* bih1 = d_in[9];
    const void* bhh1 = d_in[10];
    const void* fcW  = d_in[11];
    const void* fcb  = d_in[12];

    if (ws_size < WS_NEEDED) return;   // fail visibly rather than corrupt

    char* ws = (char*)d_ws;
    u16*   cbf  = (u16*)(ws + OFF_CBF);
    float* ch0  = (float*)(ws + OFF_CH0);
    float* cc0  = (float*)(ws + OFF_CC0);
    u16*   pw   = (u16*)(ws + OFF_PACK);
    int*   dflag= (int*)(ws + OFF_FLG + FO_DTF);
    u16*   y1buf= (u16*)(ws + OFF_Y1);

    // zero only the flag/watermark region (rings are flag-gated)
    hipMemsetAsync(ws + OFF_FLG, 0, 4160, stream);

    detect_kernel<<<1, 256, 0, stream>>>(Wih0, dflag);
    prep_kernel<<<512, 256, 0, stream>>>(Wih0, Whh0, bih0, bhh0,
                                         Wih1, Whh1, bih1, bhh1,
                                         fcW, fcb, h0, c0, cbf, ch0, cc0, dflag);
    pack_kernel<<<256, 256, 0, stream>>>(cbf, pw);
    lstm_pipe<<<40, 512, 0, stream>>>(inp, ws, dflag, d_out);
    fc_kernel<<<8192, 256, 0, stream>>>(y1buf, cbf, dflag, d_out);
}